// Round 5
// baseline (3842.620 us; speedup 1.0000x reference)
//
#include <hip/hip_runtime.h>
#include <hip/hip_bf16.h>

// Model constants
#define B_ 64
#define IMG_ 224
#define P_ 16
#define G_ 14
#define NP_ 196
#define N_ 197
#define DIM_ 384
#define DEPTH_ 12
#define H_ 12
#define DH_ 32
#define INNER_ 384
#define MLP_ 1536
#define NCLS_ 1000
#define PD_ 1792
#define EPS_ 1e-5f

typedef __hip_bfloat16 bf16;
using bf16x8 = __attribute__((ext_vector_type(8))) short;   // 8 bf16 (4 VGPRs)
using f32x4  = __attribute__((ext_vector_type(4))) float;   // MFMA acc

__device__ __forceinline__ float b2f(bf16 x) { return __bfloat162float(x); }
__device__ __forceinline__ bf16 f2b(float x) { return __float2bfloat16(x); }
__device__ __forceinline__ short f2b_raw(float f) {
    unsigned x = __float_as_uint(f);
    unsigned r = (x + 0x7FFFu + ((x >> 16) & 1u)) >> 16;
    return (short)r;
}

// ---------------------------------------------------------------- weight f32->bf16
__global__ __launch_bounds__(256) void wconv_kernel(const float* __restrict__ src,
                                                    bf16* __restrict__ dst, int n4) {
    int i = blockIdx.x * 256 + threadIdx.x;
    if (i >= n4) return;
    float4 v = ((const float4*)src)[i];
    short4 o;
    o.x = f2b_raw(v.x); o.y = f2b_raw(v.y);
    o.z = f2b_raw(v.z); o.w = f2b_raw(v.w);
    ((short4*)dst)[i] = o;
}

// ---------------------------------------------------------------- mean image (bf16)
__global__ __launch_bounds__(256) void mean_kernel(const float* __restrict__ img,
                                                   bf16* __restrict__ meanimg) {
    int idx = blockIdx.x * 256 + threadIdx.x;
    if (idx >= B_ * 50176) return;
    int b = idx / 50176;
    int yx = idx - b * 50176;
    const float* p = img + (size_t)b * 3 * 50176 + yx;
    meanimg[idx] = f2b((p[0] + p[50176] + p[100352]) * (1.0f / 3.0f));
}

// ------------------------------------------------------------- patch matrix (chunked)
__global__ __launch_bounds__(256) void patches_kernel(const float* __restrict__ img,
                                                      const bf16* __restrict__ meanimg,
                                                      bf16* __restrict__ patches,
                                                      int bp0, int nbp) {
    int idx = blockIdx.x * 256 + threadIdx.x;
    if (idx >= nbp * 256) return;
    int pix = idx & 255;
    int px = pix & 15, py = pix >> 4;
    int lbp = idx >> 8;
    int bp = bp0 + lbp;
    int p = bp % NP_;
    int b = bp / NP_;
    int gy = p / G_, gx = p - gy * G_;
    int y = gy * P_ + py, x = gx * P_ + px;
    const float* ib = img + (size_t)b * 3 * 50176 + y * 224 + x;
    bf16* out = patches + (size_t)lbp * PD_ + pix * 7;
    out[0] = f2b(ib[0]);
    out[1] = f2b(ib[50176]);
    out[2] = f2b(ib[100352]);
    const bf16* mb = meanimg + (size_t)b * 50176;
    out[3] = (x >= 8)  ? mb[y * 224 + x - 8]   : f2b(0.0f);   // l2
    out[4] = (x < 216) ? mb[y * 224 + x + 8]   : f2b(0.0f);   // r2
    out[5] = (y >= 8)  ? mb[(y - 8) * 224 + x] : f2b(0.0f);   // t2
    out[6] = (y < 216) ? mb[(y + 8) * 224 + x] : f2b(0.0f);   // b2
}

// --------------------------------------------------- cls + pos_emb assembly
__global__ __launch_bounds__(256) void addpos_kernel(const bf16* __restrict__ pe,
                                                     const float* __restrict__ cls_tok,
                                                     const float* __restrict__ pos_emb,
                                                     float* __restrict__ x) {
    int idx = blockIdx.x * 256 + threadIdx.x;
    if (idx >= B_ * N_ * DIM_) return;
    int c = idx % DIM_;
    int r = idx / DIM_;
    int t = r % N_;
    int b = r / N_;
    float v = (t == 0) ? cls_tok[c]
                       : b2f(pe[((size_t)(b * NP_ + t - 1)) * DIM_ + c]);
    x[idx] = v + pos_emb[t * DIM_ + c];
}

// ------------------------------------------------------------------ layernorm
__global__ __launch_bounds__(256) void ln_kernel(const float* __restrict__ in,
                                                 long in_stride,
                                                 const float* __restrict__ g,
                                                 const float* __restrict__ bb,
                                                 bf16* __restrict__ out, int rows) {
    int wave = threadIdx.x >> 6;
    int lane = threadIdx.x & 63;
    int row = blockIdx.x * 4 + wave;
    if (row >= rows) return;
    const float* p = in + (size_t)row * in_stride;
    float v[6];
    float s = 0.0f, s2 = 0.0f;
#pragma unroll
    for (int i = 0; i < 6; i++) {
        v[i] = p[lane + 64 * i];
        s += v[i];
        s2 += v[i] * v[i];
    }
#pragma unroll
    for (int m = 32; m >= 1; m >>= 1) {
        s += __shfl_xor(s, m);
        s2 += __shfl_xor(s2, m);
    }
    float mu = s * (1.0f / 384.0f);
    float var = s2 * (1.0f / 384.0f) - mu * mu;
    var = fmaxf(var, 0.0f);
    float inv = rsqrtf(var + EPS_);
    bf16* q = out + (size_t)row * DIM_;
#pragma unroll
    for (int i = 0; i < 6; i++) {
        int c = lane + 64 * i;
        q[c] = f2b((v[i] - mu) * inv * g[c] + bb[c]);
    }
}

// ------------------------------------------------------------------ head GEMM (wave/col)
__global__ __launch_bounds__(256) void head_kernel(const bf16* __restrict__ cls,
                                                   const float* __restrict__ W,
                                                   const float* __restrict__ bias,
                                                   float* __restrict__ out) {
    int wv = threadIdx.x >> 6, lane = threadIdx.x & 63;
    int col = blockIdx.x * 4 + wv;
    if (col >= NCLS_) return;
    const float* wp = W + (size_t)col * DIM_;
    float wreg[6];
#pragma unroll
    for (int i = 0; i < 6; i++) wreg[i] = wp[i * 64 + lane];
    float hb = bias[col];
    float res = 0.0f;
    for (int r = 0; r < 64; r++) {
        const bf16* ar = cls + r * DIM_;
        float s = 0.0f;
#pragma unroll
        for (int i = 0; i < 6; i++) s += b2f(ar[i * 64 + lane]) * wreg[i];
#pragma unroll
        for (int m = 32; m >= 1; m >>= 1) s += __shfl_xor(s, m);
        if (lane == r) res = s + hb;
    }
    out[(size_t)lane * NCLS_ + col] = res;
}

// ------------------------------------------------------------------ MFMA GEMM v7 (LDS-free, direct L2)
// C[M,N] = A[M,K] @ W[N,K]^T, both bf16. BM=128 BN=128 BK=32.
// Diagnosis r1-r4: time == LDS-staged bytes / ~5 TB/s device-wide; the
// global_load_lds FILL PATH is the binding resource, independent of barrier/
// vmcnt/swizzle structure. Escape: skip LDS entirely. The MFMA A/B fragment
// pattern (16 rows x 16 B/lane at A + r*K + k*32 + quad*8) is itself a fully
// coalesced global_load_dwordx4, so each wave loads its fragments straight
// into VGPRs, register-double-buffered (NK is always even here). No LDS, no
// barriers: waves are self-paced (max TLP), duplication (A x2, B x2 per block)
// is absorbed by per-XCD L2 (34.5 TB/s >> 5 TB/s) with the XCD-aware swizzle
// colocating same-A-panel blocks. Fragment indexing identical to mgemm3's
// ds_read pattern -> bit-identical numerics.
// MODE 0: bias. 1: bias+res(f32). 2: bias+exact GELU. N%128==0, K%64==0.
template <int MODE, typename OutT>
__global__ __launch_bounds__(256) void mgemm7_kernel(const bf16* __restrict__ A,
                                                     const bf16* __restrict__ W,
                                                     const float* __restrict__ bias,
                                                     const float* __restrict__ res,
                                                     OutT* __restrict__ C,
                                                     int M, int N, int K) {
    int tid = threadIdx.x;
    int wv = tid >> 6, lane = tid & 63;
    int ml = lane & 15, quad = lane >> 4;

    // ---- XCD-aware bijective remap (nwg need not be divisible by 8) ----
    unsigned gx = gridDim.x;
    unsigned nwg = gx * gridDim.y;
    unsigned lid = blockIdx.y * gx + blockIdx.x;
    unsigned qc = nwg >> 3, rc = nwg & 7u;
    unsigned xcd = lid & 7u, loc = lid >> 3;
    unsigned nlid = (xcd < rc ? xcd * (qc + 1u)
                              : rc * (qc + 1u) + (xcd - rc) * qc) + loc;
    unsigned bx = nlid % gx, by = nlid / gx;
    int rowBase = by * 128, colBase = bx * 128;

    int wr = (wv >> 1) * 64, wc = (wv & 1) * 64;

    // per-lane fragment base pointers (16 B aligned: K*2 % 16 == 0 for all uses)
    const bf16* ap[4];
    const bf16* bp[4];
#pragma unroll
    for (int rg = 0; rg < 4; rg++) {
        int r = rowBase + wr + rg * 16 + ml;
        if (r >= M) r = M - 1;
        ap[rg] = A + (size_t)r * K + quad * 8;
    }
#pragma unroll
    for (int cg = 0; cg < 4; cg++) {
        int c = colBase + wc + cg * 16 + ml;   // N % 128 == 0 -> always in range
        bp[cg] = W + (size_t)c * K + quad * 8;
    }

    f32x4 acc[4][4] = {};
    int NK = K >> 5;                            // even for all uses (12/48/56)

    bf16x8 a0[4], b0[4], a1[4], b1[4];

#define LOADF(as, bs, k0)                                                     \
    do {                                                                      \
        _Pragma("unroll")                                                     \
        for (int rg = 0; rg < 4; rg++) as[rg] = *(const bf16x8*)(ap[rg] + (k0)); \
        _Pragma("unroll")                                                     \
        for (int cg = 0; cg < 4; cg++) bs[cg] = *(const bf16x8*)(bp[cg] + (k0)); \
    } while (0)

#define MFMA16(as, bs)                                                        \
    do {                                                                      \
        _Pragma("unroll")                                                     \
        for (int rg = 0; rg < 4; rg++)                                        \
            _Pragma("unroll")                                                 \
            for (int cg = 0; cg < 4; cg++)                                    \
                acc[rg][cg] = __builtin_amdgcn_mfma_f32_16x16x32_bf16(        \
                    as[rg], bs[cg], acc[rg][cg], 0, 0, 0);                    \
    } while (0)

    LOADF(a0, b0, 0);
    for (int k = 0; k < NK; k += 2) {
        LOADF(a1, b1, (k + 1) * 32);            // prefetch odd step
        MFMA16(a0, b0);
        if (k + 2 < NK) LOADF(a0, b0, (k + 2) * 32);   // prefetch next even step
        MFMA16(a1, b1);
    }
#undef LOADF
#undef MFMA16

    float bval[4];
#pragma unroll
    for (int cg = 0; cg < 4; cg++)
        bval[cg] = bias ? bias[colBase + wc + cg * 16 + ml] : 0.0f;

#pragma unroll
    for (int rg = 0; rg < 4; rg++) {
#pragma unroll
        for (int reg = 0; reg < 4; reg++) {
            int r = rowBase + wr + rg * 16 + quad * 4 + reg;
            if (r >= M) continue;
            size_t ro = (size_t)r * N;
#pragma unroll
            for (int cg = 0; cg < 4; cg++) {
                int c = colBase + wc + cg * 16 + ml;
                float v = acc[rg][cg][reg] + bval[cg];
                if constexpr (MODE == 1) v += res[ro + c];
                if constexpr (MODE == 2) v = 0.5f * v * (1.0f + erff(v * 0.70710678118f));
                C[ro + c] = (OutT)v;
            }
        }
    }
}

// ------------------------------------------------------------------ MFMA GEMM v1 (base tier, W f32)
template <int MODE, typename OutT>
__global__ __launch_bounds__(256) void mgemm_kernel(const bf16* __restrict__ A,
                                                    const float* __restrict__ W,
                                                    const float* __restrict__ bias,
                                                    const float* __restrict__ res,
                                                    OutT* __restrict__ C,
                                                    int M, int N, int K) {
    __shared__ __align__(16) short lds_a[128 * 32];
    __shared__ __align__(16) short lds_b[64 * 32];
    int tid = threadIdx.x;
    int rowBase = blockIdx.y * 128;
    int colBase = blockIdx.x * 64;
    int w = tid >> 6, lane = tid & 63;
    int ml = lane & 15, kseg = lane >> 4;

    int ar = tid >> 1;
    int ah = (tid & 1) * 16;
    int agr = rowBase + ar;
    if (agr > M - 1) agr = M - 1;
    const float4* asrc_base = (const float4*)(A + (size_t)agr * K + ah);
    int br = tid >> 2;
    int bs = (tid & 3) * 8;
    const float4* wsrc_base = (const float4*)(W + (size_t)(colBase + br) * K + bs);

    f32x4 acc[2][4] = {};

    for (int k0 = 0; k0 < K; k0 += 32) {
        const float4* asrc = (const float4*)((const bf16*)asrc_base + k0);
        float4 av0 = asrc[0];
        float4 av1 = asrc[1];
        const float4* wsrc = (const float4*)((const float*)wsrc_base + k0);
        float4 w0 = wsrc[0];
        float4 w1 = wsrc[1];
        bf16x8 wb;
        wb[0] = f2b_raw(w0.x); wb[1] = f2b_raw(w0.y);
        wb[2] = f2b_raw(w0.z); wb[3] = f2b_raw(w0.w);
        wb[4] = f2b_raw(w1.x); wb[5] = f2b_raw(w1.y);
        wb[6] = f2b_raw(w1.z); wb[7] = f2b_raw(w1.w);
        __syncthreads();
        *(float4*)(lds_a + ar * 32 + ah) = av0;
        *(float4*)(lds_a + ar * 32 + ah + 8) = av1;
        *(bf16x8*)(lds_b + br * 32 + bs) = wb;
        __syncthreads();
        bf16x8 af0 = *(const bf16x8*)(lds_a + (w * 32 + ml) * 32 + kseg * 8);
        bf16x8 af1 = *(const bf16x8*)(lds_a + (w * 32 + 16 + ml) * 32 + kseg * 8);
#pragma unroll
        for (int ct = 0; ct < 4; ct++) {
            bf16x8 bf_ = *(const bf16x8*)(lds_b + (ct * 16 + ml) * 32 + kseg * 8);
            acc[0][ct] = __builtin_amdgcn_mfma_f32_16x16x32_bf16(af0, bf_, acc[0][ct], 0, 0, 0);
            acc[1][ct] = __builtin_amdgcn_mfma_f32_16x16x32_bf16(af1, bf_, acc[1][ct], 0, 0, 0);
        }
    }

    float bval[4];
#pragma unroll
    for (int ct = 0; ct < 4; ct++)
        bval[ct] = bias ? bias[colBase + ct * 16 + ml] : 0.0f;

#pragma unroll
    for (int rt = 0; rt < 2; rt++) {
#pragma unroll
        for (int reg = 0; reg < 4; reg++) {
            int r = rowBase + w * 32 + rt * 16 + kseg * 4 + reg;
            if (r >= M) continue;
            size_t ro = (size_t)r * N;
#pragma unroll
            for (int ct = 0; ct < 4; ct++) {
                int c = colBase + ct * 16 + ml;
                float v = acc[rt][ct][reg] + bval[ct];
                if constexpr (MODE == 1) v += res[ro + c];
                if constexpr (MODE == 2) v = 0.5f * v * (1.0f + erff(v * 0.70710678118f));
                C[ro + c] = (OutT)v;
            }
        }
    }
}

// ------------------------------------------------------------------ MFMA attention
#define AKR 208
#define VTS 232
#define PSS 232
__global__ __launch_bounds__(256) void attn_mfma_kernel(const bf16* __restrict__ qkv,
                                                        const float* __restrict__ scale,
                                                        bf16* __restrict__ o) {
    __shared__ __align__(16) short Ks[AKR * 32];
    __shared__ __align__(16) short Vt[32 * VTS];
    __shared__ __align__(16) short Ps[4][16 * PSS];
    int b = blockIdx.x, h = blockIdx.y;
    int tid = threadIdx.x;
    int w = tid >> 6, lane = tid & 63;
    int ml = lane & 15, quad = lane >> 4;

    for (int i = tid; i < 32 * VTS / 2; i += 256) ((int*)Vt)[i] = 0;
    for (int e = lane; e < 16 * 16; e += 64) {
        int r = e >> 4, c = e & 15;
        Ps[w][r * PSS + 208 + c] = 0;
    }
    __syncthreads();
    for (int e = tid; e < AKR * 4; e += 256) {
        int row = e >> 2, seg = e & 3;
        float4 v = {0.0f, 0.0f, 0.0f, 0.0f};
        if (row < N_)
            v = *(const float4*)(qkv + (size_t)(b * N_ + row) * (3 * INNER_) + INNER_ + h * DH_ + seg * 8);
        *(float4*)(Ks + row * 32 + seg * 8) = v;
    }
    for (int e = tid; e < N_ * 32; e += 256) {
        int j = e >> 5, d = e & 31;
        Vt[d * VTS + j] = *(const short*)(qkv + (size_t)(b * N_ + j) * (3 * INNER_) + 2 * INNER_ + h * DH_ + d);
    }
    __syncthreads();

    float sc = scale[h];
    for (int qt = w; qt < 13; qt += 4) {
        int q0 = qt * 16;
        int qrow = q0 + ml;
        if (qrow > N_ - 1) qrow = N_ - 1;
        bf16x8 aq = *(const bf16x8*)(qkv + (size_t)(b * N_ + qrow) * (3 * INNER_) + h * DH_ + quad * 8);
        f32x4 accs[13];
#pragma unroll
        for (int kt = 0; kt < 13; kt++) {
            bf16x8 bk = *(const bf16x8*)(Ks + (kt * 16 + ml) * 32 + quad * 8);
            f32x4 z = {0.0f, 0.0f, 0.0f, 0.0f};
            accs[kt] = __builtin_amdgcn_mfma_f32_16x16x32_bf16(aq, bk, z, 0, 0, 0);
        }
        float rmax[4] = {-1e30f, -1e30f, -1e30f, -1e30f};
#pragma unroll
        for (int kt = 0; kt < 13; kt++) {
            int key = kt * 16 + ml;
#pragma unroll
            for (int reg = 0; reg < 4; reg++) {
                int qg = q0 + quad * 4 + reg;
                bool valid = (key < N_) && (key != qg);
                float s = valid ? accs[kt][reg] * sc : -1e30f;
                accs[kt][reg] = s;
                rmax[reg] = fmaxf(rmax[reg], s);
            }
        }
#pragma unroll
        for (int m = 1; m <= 8; m <<= 1)
#pragma unroll
            for (int reg = 0; reg < 4; reg++)
                rmax[reg] = fmaxf(rmax[reg], __shfl_xor(rmax[reg], m));
        float rsum[4] = {0.0f, 0.0f, 0.0f, 0.0f};
#pragma unroll
        for (int kt = 0; kt < 13; kt++) {
#pragma unroll
            for (int reg = 0; reg < 4; reg++) {
                float wgt = __expf(accs[kt][reg] - rmax[reg]);
                accs[kt][reg] = wgt;
                rsum[reg] += wgt;
            }
        }
#pragma unroll
        for (int m = 1; m <= 8; m <<= 1)
#pragma unroll
            for (int reg = 0; reg < 4; reg++)
                rsum[reg] += __shfl_xor(rsum[reg], m);
#pragma unroll
        for (int kt = 0; kt < 13; kt++)
#pragma unroll
            for (int reg = 0; reg < 4; reg++)
                Ps[w][(quad * 4 + reg) * PSS + kt * 16 + ml] = f2b_raw(accs[kt][reg]);
        f32x4 acco[2] = {{0.0f, 0.0f, 0.0f, 0.0f}, {0.0f, 0.0f, 0.0f, 0.0f}};
#pragma unroll
        for (int kc = 0; kc < 7; kc++) {
            bf16x8 ap2 = *(const bf16x8*)(Ps[w] + ml * PSS + kc * 32 + quad * 8);
#pragma unroll
            for (int nt = 0; nt < 2; nt++) {
                bf16x8 bv = *(const bf16x8*)(Vt + (nt * 16 + ml) * VTS + kc * 32 + quad * 8);
                acco[nt] = __builtin_amdgcn_mfma_f32_16x16x32_bf16(ap2, bv, acco[nt], 0, 0, 0);
            }
        }
#pragma unroll
        for (int reg = 0; reg < 4; reg++) {
            int qg = q0 + quad * 4 + reg;
            if (qg >= N_) continue;
            float inv = 1.0f / rsum[reg];
#pragma unroll
            for (int nt = 0; nt < 2; nt++)
                o[(size_t)(b * N_ + qg) * INNER_ + h * DH_ + nt * 16 + ml] = f2b(acco[nt][reg] * inv);
        }
    }
}

// ------------------------------------------------------------------ diagnostics (f32 out)
__global__ __launch_bounds__(256) void diag_kernel(const float* __restrict__ bufx,
                                                   float* __restrict__ outf,
                                                   int base_marker, int ran) {
    __shared__ int bad;
    if (threadIdx.x == 0) bad = 0;
    __syncthreads();
    if (ran) {
        for (int i = threadIdx.x; i < 4096; i += 256) {
            float v = bufx[i];
            if (!(fabsf(v) < 1e30f)) bad = 1;
        }
    }
    __syncthreads();
    int marker = base_marker + (bad ? 512 : 0);
    if (marker == 0) return;
    int idx = blockIdx.x * 256 + threadIdx.x;
    if (idx > 0 && idx < 64000) outf[idx] = 0.0f;
    if (idx == 0) outf[0] = (float)marker;
}

// ------------------------------------------------------------------ launch
extern "C" void kernel_launch(void* const* d_in, const int* in_sizes, int n_in,
                              void* d_out, int out_size, void* d_ws, size_t ws_size,
                              hipStream_t stream) {
    const float* img     = (const float*)d_in[0];
    const float* patch_w = (const float*)d_in[1];
    const float* patch_b = (const float*)d_in[2];
    const float* pos_emb = (const float*)d_in[3];
    const float* cls_tok = (const float*)d_in[4];
    const float* ln1_g   = (const float*)d_in[5];
    const float* ln1_b   = (const float*)d_in[6];
    const float* qkv_w   = (const float*)d_in[7];
    const float* scale   = (const float*)d_in[8];
    const float* out_w   = (const float*)d_in[9];
    const float* out_b   = (const float*)d_in[10];
    const float* ln2_g   = (const float*)d_in[11];
    const float* ln2_b   = (const float*)d_in[12];
    const float* ff_w1   = (const float*)d_in[13];
    const float* ff_b1   = (const float*)d_in[14];
    const float* ff_w2   = (const float*)d_in[15];
    const float* ff_b2   = (const float*)d_in[16];
    const float* lnf_g   = (const float*)d_in[17];
    const float* lnf_b   = (const float*)d_in[18];
    const float* head_w  = (const float*)d_in[19];
    const float* head_b  = (const float*)d_in[20];

    const size_t NEED      = 58146816;
    const size_t NEED_FAST = 101990400;
    const size_t NEED_FULL = 140722176;
    char* ws = (char*)d_ws;
    const int ROWS = B_ * N_;  // 12608
    const int GY = (ROWS + 127) / 128;  // 99

    if (ws_size < NEED) {
        diag_kernel<<<250, 256, 0, stream>>>((const float*)d_out, (float*)d_out,
                                             1024 + (int)(ws_size >> 20), 0);
        return;
    }

    float* buf_x  = (float*)ws;                    // 19,365,888 (all tiers)
    bf16*  buf_hb = (bf16*)(ws + 19365888);        //  9,682,944 (all tiers)

    if (ws_size >= NEED_FAST) {
        // ---- bf16-weight tiers (FAST / FULL) ----
        bool full = (ws_size >= NEED_FULL);
        bf16 *buf_qkv, *buf_ff, *buf_patch, *meanimg, *buf_cls;
        bf16 *wb_patch, *wb_qkv, *wb_out, *wb_ff1, *wb_ff2;
        int pchunks, fchunks;
        if (full) {
            buf_qkv  = (bf16*)(ws + 29048832);
            buf_ff   = (bf16*)(ws + 58097664);
            buf_patch= (bf16*)(ws + 29048832);
            meanimg  = (bf16*)(ws + 74006528);
            wb_patch = (bf16*)(ws + 96829440);
            wb_qkv   = (bf16*)(ws + 98205696);
            wb_out   = (bf16*)(ws + 108822528);
            wb_ff1   = (bf16*)(ws + 112361472);
            wb_ff2   = (bf16*)(ws + 126517248);
            buf_cls  = (bf16*)(ws + 140673024);
            pchunks = 1; fchunks = 1;
        } else {
            buf_qkv  = (bf16*)(ws + 29048832);
            buf_ff   = (bf16*)(ws + 29048832);
            buf_patch= (bf16*)(ws + 29048832);
            meanimg  = (bf16*)(ws + 29048832 + 22478848);
            buf_cls  = (bf16*)(ws + 58097664);
            wb_patch = (bf16*)(ws + 58146816);
            wb_qkv   = (bf16*)(ws + 59523072);
            wb_out   = (bf16*)(ws + 70139904);
            wb_ff1   = (bf16*)(ws + 73678848);
            wb_ff2   = (bf16*)(ws + 87834624);
            pchunks = 2; fchunks = 2;
        }

        wconv_kernel<<<(688128 / 4 + 255) / 256, 256, 0, stream>>>(patch_w, wb_patch, 688128 / 4);
        wconv_kernel<<<(5308416 / 4 + 255) / 256, 256, 0, stream>>>(qkv_w, wb_qkv, 5308416 / 4);
        wconv_kernel<<<(1769472 / 4 + 255) / 256, 256, 0, stream>>>(out_w, wb_out, 1769472 / 4);
        wconv_kernel<<<(7077888 / 4 + 255) / 256, 256, 0, stream>>>(ff_w1, wb_ff1, 7077888 / 4);
        wconv_kernel<<<(7077888 / 4 + 255) / 256, 256, 0, stream>>>(ff_w2, wb_ff2, 7077888 / 4);

        mean_kernel<<<(B_ * 50176 + 255) / 256, 256, 0, stream>>>(img, meanimg);
        for (int c = 0; c < pchunks; c++) {
            int bp0 = c * (12544 / pchunks);
            int nbp = 12544 / pchunks;
            patches_kernel<<<nbp, 256, 0, stream>>>(img, meanimg, buf_patch, bp0, nbp);
            mgemm7_kernel<0, bf16><<<dim3(3, (nbp + 127) / 128), 256, 0, stream>>>(
                buf_patch, wb_patch, patch_b, nullptr, buf_hb + (size_t)bp0 * DIM_, nbp, DIM_, PD_);
        }
        addpos_kernel<<<(B_ * N_ * DIM_ + 255) / 256, 256, 0, stream>>>(buf_hb, cls_tok, pos_emb, buf_x);

        for (int i = 0; i < DEPTH_; i++) {
            ln_kernel<<<ROWS / 4, 256, 0, stream>>>(buf_x, DIM_, ln1_g + i * DIM_,
                                                    ln1_b + i * DIM_, buf_hb, ROWS);
            mgemm7_kernel<0, bf16><<<dim3(9, GY), 256, 0, stream>>>(
                buf_hb, wb_qkv + (size_t)i * 3 * INNER_ * DIM_, nullptr, nullptr, buf_qkv,
                ROWS, 3 * INNER_, DIM_);
            attn_mfma_kernel<<<dim3(B_, H_), 256, 0, stream>>>(buf_qkv, scale + i * H_, buf_hb);
            mgemm7_kernel<1, float><<<dim3(3, GY), 256, 0, stream>>>(
                buf_hb, wb_out + (size_t)i * DIM_ * INNER_, out_b + i * DIM_, buf_x, buf_x,
                ROWS, DIM_, INNER_);
            ln_kernel<<<ROWS / 4, 256, 0, stream>>>(buf_x, DIM_, ln2_g + i * DIM_,
                                                    ln2_b + i * DIM_, buf_hb, ROWS);
            int base = 0;
            for (int c = 0; c < fchunks; c++) {
                int mrows = (fchunks == 1) ? ROWS : ((c == 0) ? 6336 : 6272);
                int gy = (mrows + 127) / 128;
                mgemm7_kernel<2, bf16><<<dim3(12, gy), 256, 0, stream>>>(
                    buf_hb + (size_t)base * DIM_, wb_ff1 + (size_t)i * MLP_ * DIM_,
                    ff_b1 + i * MLP_, nullptr, buf_ff, mrows, MLP_, DIM_);
                mgemm7_kernel<1, float><<<dim3(3, gy), 256, 0, stream>>>(
                    buf_ff, wb_ff2 + (size_t)i * DIM_ * MLP_, ff_b2 + i * DIM_,
                    buf_x + (size_t)base * DIM_, buf_x + (size_t)base * DIM_, mrows, DIM_, MLP_);
                base += mrows;
            }
        }

        ln_kernel<<<B_ / 4, 256, 0, stream>>>(buf_x, (long)N_ * DIM_, lnf_g, lnf_b, buf_cls, B_);
        head_kernel<<<250, 256, 0, stream>>>(buf_cls, head_w, head_b, (float*)d_out);
        diag_kernel<<<250, 256, 0, stream>>>(buf_x, (float*)d_out, 0, 1);
        return;
    }

    // ---- base tier: round-7 proven path (W f32 in-kernel convert) ----
    bf16* buf_cd   = (bf16*)(ws + 29048832);
    bf16* meanimg  = (bf16*)(ws + 29048832 + 22478848);
    bf16* buf_cls  = (bf16*)(ws + 58097664);

    mean_kernel<<<(B_ * 50176 + 255) / 256, 256, 0, stream>>>(img, meanimg);
    for (int c = 0; c < 2; c++) {
        int bp0 = c * 6272;
        patches_kernel<<<6272, 256, 0, stream>>>(img, meanimg, buf_cd, bp0, 6272);
        mgemm_kernel<0, bf16><<<dim3(DIM_ / 64, 49), 256, 0, stream>>>(
            buf_cd, patch_w, patch_b, nullptr, buf_hb + (size_t)bp0 * DIM_, 6272, DIM_, PD_);
    }
    addpos_kernel<<<(B_ * N_ * DIM_ + 255) / 256, 256, 0, stream>>>(buf_hb, cls_tok, pos_emb, buf_x);

    for (int i = 0; i < DEPTH_; i++) {
        ln_kernel<<<ROWS / 4, 256, 0, stream>>>(buf_x, DIM_, ln1_g + i * DIM_,
                                                ln1_b + i * DIM_, buf_hb, ROWS);
        mgemm_kernel<0, bf16><<<dim3((3 * INNER_) / 64, GY), 256, 0, stream>>>(
            buf_hb, qkv_w + (size_t)i * 3 * INNER_ * DIM_, nullptr, nullptr, buf_cd,
            ROWS, 3 * INNER_, DIM_);
        attn_mfma_kernel<<<dim3(B_, H_), 256, 0, stream>>>(buf_cd, scale + i * H_, buf_hb);
        mgemm_kernel<1, float><<<dim3(DIM_ / 64, GY), 256, 0, stream>>>(
            buf_hb, out_w + (size_t)i * DIM_ * INNER_, out_b + i * DIM_, buf_x, buf_x,
            ROWS, DIM_, INNER_);
        ln_kernel<<<ROWS / 4, 256, 0, stream>>>(buf_x, DIM_, ln2_g + i * DIM_,
                                                ln2_b + i * DIM_, buf_hb, ROWS);
        int base = 0;
        for (int c = 0; c < 2; c++) {
            int mrows = (c == 0) ? 6336 : 6272;
            int gy = (mrows + 127) / 128;
            mgemm_kernel<2, bf16><<<dim3(MLP_ / 64, gy), 256, 0, stream>>>(
                buf_hb + (size_t)base * DIM_, ff_w1 + (size_t)i * MLP_ * DIM_,
                ff_b1 + i * MLP_, nullptr, buf_cd, mrows, MLP_, DIM_);
            mgemm_kernel<1, float><<<dim3(DIM_ / 64, gy), 256, 0, stream>>>(
                buf_cd, ff_w2 + (size_t)i * DIM_ * MLP_, ff_b2 + i * DIM_,
                buf_x + (size_t)base * DIM_, buf_x + (size_t)base * DIM_, mrows, DIM_, MLP_);
            base += mrows;
        }
    }

    ln_kernel<<<B_ / 4, 256, 0, stream>>>(buf_x, (long)N_ * DIM_, lnf_g, lnf_b, buf_cls, B_);
    head_kernel<<<250, 256, 0, stream>>>(buf_cls, head_w, head_b, (float*)d_out);
    diag_kernel<<<250, 256, 0, stream>>>(buf_x, (float*)d_out, 0, 1);
}

// Round 6
// 2307.728 us; speedup vs baseline: 1.6651x; 1.6651x over previous
//
#include <hip/hip_runtime.h>
#include <hip/hip_bf16.h>

// Model constants
#define B_ 64
#define IMG_ 224
#define P_ 16
#define G_ 14
#define NP_ 196
#define N_ 197
#define DIM_ 384
#define DEPTH_ 12
#define H_ 12
#define DH_ 32
#define INNER_ 384
#define MLP_ 1536
#define NCLS_ 1000
#define PD_ 1792
#define EPS_ 1e-5f

typedef __hip_bfloat16 bf16;
using bf16x8 = __attribute__((ext_vector_type(8))) short;   // 8 bf16 (4 VGPRs)
using f32x4  = __attribute__((ext_vector_type(4))) float;   // MFMA acc

__device__ __forceinline__ float b2f(bf16 x) { return __bfloat162float(x); }
__device__ __forceinline__ bf16 f2b(float x) { return __float2bfloat16(x); }
__device__ __forceinline__ short f2b_raw(float f) {
    unsigned x = __float_as_uint(f);
    unsigned r = (x + 0x7FFFu + ((x >> 16) & 1u)) >> 16;
    return (short)r;
}
// raw workgroup barrier WITHOUT implicit vmcnt(0) drain
__device__ __forceinline__ void barrier_raw() {
    asm volatile("s_barrier" ::: "memory");
}
__device__ __forceinline__ void lgkm0() {
    asm volatile("s_waitcnt lgkmcnt(0)" ::: "memory");
}

// ---------------------------------------------------------------- weight f32->bf16
__global__ __launch_bounds__(256) void wconv_kernel(const float* __restrict__ src,
                                                    bf16* __restrict__ dst, int n4) {
    int i = blockIdx.x * 256 + threadIdx.x;
    if (i >= n4) return;
    float4 v = ((const float4*)src)[i];
    short4 o;
    o.x = f2b_raw(v.x); o.y = f2b_raw(v.y);
    o.z = f2b_raw(v.z); o.w = f2b_raw(v.w);
    ((short4*)dst)[i] = o;
}

// ---------------------------------------------------------------- mean image (bf16)
__global__ __launch_bounds__(256) void mean_kernel(const float* __restrict__ img,
                                                   bf16* __restrict__ meanimg) {
    int idx = blockIdx.x * 256 + threadIdx.x;
    if (idx >= B_ * 50176) return;
    int b = idx / 50176;
    int yx = idx - b * 50176;
    const float* p = img + (size_t)b * 3 * 50176 + yx;
    meanimg[idx] = f2b((p[0] + p[50176] + p[100352]) * (1.0f / 3.0f));
}

// ------------------------------------------------------------- patch matrix (chunked)
__global__ __launch_bounds__(256) void patches_kernel(const float* __restrict__ img,
                                                      const bf16* __restrict__ meanimg,
                                                      bf16* __restrict__ patches,
                                                      int bp0, int nbp) {
    int idx = blockIdx.x * 256 + threadIdx.x;
    if (idx >= nbp * 256) return;
    int pix = idx & 255;
    int px = pix & 15, py = pix >> 4;
    int lbp = idx >> 8;
    int bp = bp0 + lbp;
    int p = bp % NP_;
    int b = bp / NP_;
    int gy = p / G_, gx = p - gy * G_;
    int y = gy * P_ + py, x = gx * P_ + px;
    const float* ib = img + (size_t)b * 3 * 50176 + y * 224 + x;
    bf16* out = patches + (size_t)lbp * PD_ + pix * 7;
    out[0] = f2b(ib[0]);
    out[1] = f2b(ib[50176]);
    out[2] = f2b(ib[100352]);
    const bf16* mb = meanimg + (size_t)b * 50176;
    out[3] = (x >= 8)  ? mb[y * 224 + x - 8]   : f2b(0.0f);   // l2
    out[4] = (x < 216) ? mb[y * 224 + x + 8]   : f2b(0.0f);   // r2
    out[5] = (y >= 8)  ? mb[(y - 8) * 224 + x] : f2b(0.0f);   // t2
    out[6] = (y < 216) ? mb[(y + 8) * 224 + x] : f2b(0.0f);   // b2
}

// --------------------------------------------------- cls + pos_emb assembly
__global__ __launch_bounds__(256) void addpos_kernel(const bf16* __restrict__ pe,
                                                     const float* __restrict__ cls_tok,
                                                     const float* __restrict__ pos_emb,
                                                     float* __restrict__ x) {
    int idx = blockIdx.x * 256 + threadIdx.x;
    if (idx >= B_ * N_ * DIM_) return;
    int c = idx % DIM_;
    int r = idx / DIM_;
    int t = r % N_;
    int b = r / N_;
    float v = (t == 0) ? cls_tok[c]
                       : b2f(pe[((size_t)(b * NP_ + t - 1)) * DIM_ + c]);
    x[idx] = v + pos_emb[t * DIM_ + c];
}

// ------------------------------------------------------------------ layernorm
__global__ __launch_bounds__(256) void ln_kernel(const float* __restrict__ in,
                                                 long in_stride,
                                                 const float* __restrict__ g,
                                                 const float* __restrict__ bb,
                                                 bf16* __restrict__ out, int rows) {
    int wave = threadIdx.x >> 6;
    int lane = threadIdx.x & 63;
    int row = blockIdx.x * 4 + wave;
    if (row >= rows) return;
    const float* p = in + (size_t)row * in_stride;
    float v[6];
    float s = 0.0f, s2 = 0.0f;
#pragma unroll
    for (int i = 0; i < 6; i++) {
        v[i] = p[lane + 64 * i];
        s += v[i];
        s2 += v[i] * v[i];
    }
#pragma unroll
    for (int m = 32; m >= 1; m >>= 1) {
        s += __shfl_xor(s, m);
        s2 += __shfl_xor(s2, m);
    }
    float mu = s * (1.0f / 384.0f);
    float var = s2 * (1.0f / 384.0f) - mu * mu;
    var = fmaxf(var, 0.0f);
    float inv = rsqrtf(var + EPS_);
    bf16* q = out + (size_t)row * DIM_;
#pragma unroll
    for (int i = 0; i < 6; i++) {
        int c = lane + 64 * i;
        q[c] = f2b((v[i] - mu) * inv * g[c] + bb[c]);
    }
}

// ------------------------------------------------------------------ head GEMM (wave/col)
__global__ __launch_bounds__(256) void head_kernel(const bf16* __restrict__ cls,
                                                   const float* __restrict__ W,
                                                   const float* __restrict__ bias,
                                                   float* __restrict__ out) {
    int wv = threadIdx.x >> 6, lane = threadIdx.x & 63;
    int col = blockIdx.x * 4 + wv;
    if (col >= NCLS_) return;
    const float* wp = W + (size_t)col * DIM_;
    float wreg[6];
#pragma unroll
    for (int i = 0; i < 6; i++) wreg[i] = wp[i * 64 + lane];
    float hb = bias[col];
    float res = 0.0f;
    for (int r = 0; r < 64; r++) {
        const bf16* ar = cls + r * DIM_;
        float s = 0.0f;
#pragma unroll
        for (int i = 0; i < 6; i++) s += b2f(ar[i * 64 + lane]) * wreg[i];
#pragma unroll
        for (int m = 32; m >= 1; m >>= 1) s += __shfl_xor(s, m);
        if (lane == r) res = s + hb;
    }
    out[(size_t)lane * NCLS_ + col] = res;
}

// ------------------------------------------------------------------ MFMA GEMM v8 (reg-staged db2)
// C[M,N] = A[M,K] @ W[N,K]^T, both bf16. BM=128 BN=128 BK=32, db2 (32 KB LDS).
// Diagnosis r1-r5: every global_load_lds-staged variant pins at ~45-48us; the
// gload_lds return path retires ~16 B/cyc/CU (scattered per-lane LDS writes),
// ~100 cyc per 1KB instruction -- this reproduces r1 AND r4 quantitatively.
// Fix: reg-staging (HipKittens' path): coalesced global_load_dwordx4 -> VGPR,
// then wave-coalesced ds_write_b128 (128 B/cyc LDS port, ~8x faster fill).
// T14 discipline: writes of tile k+1 + loads of tile k+2 issued AFTER MFMA of
// tile k; only lgkmcnt(0) drained before the raw s_barrier -- global loads stay
// in flight across it. Compiler inserts the counted vmcnt before the dependent
// ds_writes. Addressing/fragments identical to mgemm3 -> identical numerics.
// MODE 0: bias. 1: bias+res(f32). 2: bias+exact GELU. N%128==0, K%32==0, K>=64.
template <int MODE, typename OutT>
__global__ __launch_bounds__(256) void mgemm8_kernel(const bf16* __restrict__ A,
                                                     const bf16* __restrict__ W,
                                                     const float* __restrict__ bias,
                                                     const float* __restrict__ res,
                                                     OutT* __restrict__ C,
                                                     int M, int N, int K) {
    __shared__ __align__(16) short lds_a[2][128 * 32];   // 2 x 8 KB
    __shared__ __align__(16) short lds_b[2][128 * 32];   // 2 x 8 KB
    int tid = threadIdx.x;
    int wv = tid >> 6, lane = tid & 63;
    int ml = lane & 15, quad = lane >> 4;

    // ---- XCD-aware bijective remap ----
    unsigned gx = gridDim.x;
    unsigned nwg = gx * gridDim.y;
    unsigned lid = blockIdx.y * gx + blockIdx.x;
    unsigned qc = nwg >> 3, rc = nwg & 7u;
    unsigned xcd = lid & 7u, loc = lid >> 3;
    unsigned nlid = (xcd < rc ? xcd * (qc + 1u)
                              : rc * (qc + 1u) + (xcd - rc) * qc) + loc;
    unsigned bx = nlid % gx, by = nlid / gx;
    int rowBase = by * 128, colBase = bx * 128;

    // staging: 4 lanes per row, 16 B per lane -> wave covers 16 rows x 64 B
    int srow = wv * 16 + (lane >> 2);       // 0..63
    int kcol = (lane & 3) * 8;              // shorts
    int ar0 = rowBase + srow;       if (ar0 >= M) ar0 = M - 1;
    int ar1 = rowBase + 64 + srow;  if (ar1 >= M) ar1 = M - 1;
    const bf16* a0 = A + (size_t)ar0 * K + kcol;
    const bf16* a1 = A + (size_t)ar1 * K + kcol;
    const bf16* b0 = W + (size_t)(colBase + srow) * K + kcol;
    const bf16* b1 = W + (size_t)(colBase + 64 + srow) * K + kcol;
    int d0 = srow * 32 + kcol;              // shorts
    int d1 = (64 + srow) * 32 + kcol;

    float4 ra0, ra1, rb0, rb1;
#define LOADR8(k0)                              \
    do {                                        \
        ra0 = *(const float4*)(a0 + (k0));      \
        ra1 = *(const float4*)(a1 + (k0));      \
        rb0 = *(const float4*)(b0 + (k0));      \
        rb1 = *(const float4*)(b1 + (k0));      \
    } while (0)
#define WRITE8(bufi)                            \
    do {                                        \
        *(float4*)(lds_a[bufi] + d0) = ra0;     \
        *(float4*)(lds_a[bufi] + d1) = ra1;     \
        *(float4*)(lds_b[bufi] + d0) = rb0;     \
        *(float4*)(lds_b[bufi] + d1) = rb1;     \
    } while (0)

    int wr = (wv >> 1) * 64, wc = (wv & 1) * 64;
    f32x4 acc[4][4] = {};
    int NK = K >> 5;                        // >= 2 for all call sites

    LOADR8(0);
    WRITE8(0);                              // compiler inserts vmcnt before writes
    LOADR8(32);                             // tile 1 in flight across barrier
    lgkm0();
    barrier_raw();

    for (int k = 0; k < NK; k++) {
        int cb = k & 1;
        bf16x8 af[4], bfr[4];
#pragma unroll
        for (int rg = 0; rg < 4; rg++)
            af[rg] = *(const bf16x8*)(lds_a[cb] + (wr + rg * 16 + ml) * 32 + quad * 8);
#pragma unroll
        for (int cg = 0; cg < 4; cg++)
            bfr[cg] = *(const bf16x8*)(lds_b[cb] + (wc + cg * 16 + ml) * 32 + quad * 8);
#pragma unroll
        for (int rg = 0; rg < 4; rg++)
#pragma unroll
            for (int cg = 0; cg < 4; cg++)
                acc[rg][cg] = __builtin_amdgcn_mfma_f32_16x16x32_bf16(af[rg], bfr[cg], acc[rg][cg], 0, 0, 0);
        if (k + 1 < NK) {
            WRITE8(cb ^ 1);                 // tile k+1 regs -> other buffer
            if (k + 2 < NK) LOADR8((k + 2) * 32);   // issue next loads, stay in flight
            lgkm0();                         // drain ds_writes only
            barrier_raw();
        }
    }
#undef LOADR8
#undef WRITE8

    float bval[4];
#pragma unroll
    for (int cg = 0; cg < 4; cg++)
        bval[cg] = bias ? bias[colBase + wc + cg * 16 + ml] : 0.0f;

#pragma unroll
    for (int rg = 0; rg < 4; rg++) {
#pragma unroll
        for (int reg = 0; reg < 4; reg++) {
            int r = rowBase + wr + rg * 16 + quad * 4 + reg;
            if (r >= M) continue;
            size_t ro = (size_t)r * N;
#pragma unroll
            for (int cg = 0; cg < 4; cg++) {
                int c = colBase + wc + cg * 16 + ml;
                float v = acc[rg][cg][reg] + bval[cg];
                if constexpr (MODE == 1) v += res[ro + c];
                if constexpr (MODE == 2) v = 0.5f * v * (1.0f + erff(v * 0.70710678118f));
                C[ro + c] = (OutT)v;
            }
        }
    }
}

// ------------------------------------------------------------------ MFMA GEMM v1 (base tier, W f32)
template <int MODE, typename OutT>
__global__ __launch_bounds__(256) void mgemm_kernel(const bf16* __restrict__ A,
                                                    const float* __restrict__ W,
                                                    const float* __restrict__ bias,
                                                    const float* __restrict__ res,
                                                    OutT* __restrict__ C,
                                                    int M, int N, int K) {
    __shared__ __align__(16) short lds_a[128 * 32];
    __shared__ __align__(16) short lds_b[64 * 32];
    int tid = threadIdx.x;
    int rowBase = blockIdx.y * 128;
    int colBase = blockIdx.x * 64;
    int w = tid >> 6, lane = tid & 63;
    int ml = lane & 15, kseg = lane >> 4;

    int ar = tid >> 1;
    int ah = (tid & 1) * 16;
    int agr = rowBase + ar;
    if (agr > M - 1) agr = M - 1;
    const float4* asrc_base = (const float4*)(A + (size_t)agr * K + ah);
    int br = tid >> 2;
    int bs = (tid & 3) * 8;
    const float4* wsrc_base = (const float4*)(W + (size_t)(colBase + br) * K + bs);

    f32x4 acc[2][4] = {};

    for (int k0 = 0; k0 < K; k0 += 32) {
        const float4* asrc = (const float4*)((const bf16*)asrc_base + k0);
        float4 av0 = asrc[0];
        float4 av1 = asrc[1];
        const float4* wsrc = (const float4*)((const float*)wsrc_base + k0);
        float4 w0 = wsrc[0];
        float4 w1 = wsrc[1];
        bf16x8 wb;
        wb[0] = f2b_raw(w0.x); wb[1] = f2b_raw(w0.y);
        wb[2] = f2b_raw(w0.z); wb[3] = f2b_raw(w0.w);
        wb[4] = f2b_raw(w1.x); wb[5] = f2b_raw(w1.y);
        wb[6] = f2b_raw(w1.z); wb[7] = f2b_raw(w1.w);
        __syncthreads();
        *(float4*)(lds_a + ar * 32 + ah) = av0;
        *(float4*)(lds_a + ar * 32 + ah + 8) = av1;
        *(bf16x8*)(lds_b + br * 32 + bs) = wb;
        __syncthreads();
        bf16x8 af0 = *(const bf16x8*)(lds_a + (w * 32 + ml) * 32 + kseg * 8);
        bf16x8 af1 = *(const bf16x8*)(lds_a + (w * 32 + 16 + ml) * 32 + kseg * 8);
#pragma unroll
        for (int ct = 0; ct < 4; ct++) {
            bf16x8 bf_ = *(const bf16x8*)(lds_b + (ct * 16 + ml) * 32 + kseg * 8);
            acc[0][ct] = __builtin_amdgcn_mfma_f32_16x16x32_bf16(af0, bf_, acc[0][ct], 0, 0, 0);
            acc[1][ct] = __builtin_amdgcn_mfma_f32_16x16x32_bf16(af1, bf_, acc[1][ct], 0, 0, 0);
        }
    }

    float bval[4];
#pragma unroll
    for (int ct = 0; ct < 4; ct++)
        bval[ct] = bias ? bias[colBase + ct * 16 + ml] : 0.0f;

#pragma unroll
    for (int rt = 0; rt < 2; rt++) {
#pragma unroll
        for (int reg = 0; reg < 4; reg++) {
            int r = rowBase + w * 32 + rt * 16 + kseg * 4 + reg;
            if (r >= M) continue;
            size_t ro = (size_t)r * N;
#pragma unroll
            for (int ct = 0; ct < 4; ct++) {
                int c = colBase + ct * 16 + ml;
                float v = acc[rt][ct][reg] + bval[ct];
                if constexpr (MODE == 1) v += res[ro + c];
                if constexpr (MODE == 2) v = 0.5f * v * (1.0f + erff(v * 0.70710678118f));
                C[ro + c] = (OutT)v;
            }
        }
    }
}

// ------------------------------------------------------------------ MFMA attention
#define AKR 208
#define VTS 232
#define PSS 232
__global__ __launch_bounds__(256) void attn_mfma_kernel(const bf16* __restrict__ qkv,
                                                        const float* __restrict__ scale,
                                                        bf16* __restrict__ o) {
    __shared__ __align__(16) short Ks[AKR * 32];
    __shared__ __align__(16) short Vt[32 * VTS];
    __shared__ __align__(16) short Ps[4][16 * PSS];
    int b = blockIdx.x, h = blockIdx.y;
    int tid = threadIdx.x;
    int w = tid >> 6, lane = tid & 63;
    int ml = lane & 15, quad = lane >> 4;

    for (int i = tid; i < 32 * VTS / 2; i += 256) ((int*)Vt)[i] = 0;
    for (int e = lane; e < 16 * 16; e += 64) {
        int r = e >> 4, c = e & 15;
        Ps[w][r * PSS + 208 + c] = 0;
    }
    __syncthreads();
    for (int e = tid; e < AKR * 4; e += 256) {
        int row = e >> 2, seg = e & 3;
        float4 v = {0.0f, 0.0f, 0.0f, 0.0f};
        if (row < N_)
            v = *(const float4*)(qkv + (size_t)(b * N_ + row) * (3 * INNER_) + INNER_ + h * DH_ + seg * 8);
        *(float4*)(Ks + row * 32 + seg * 8) = v;
    }
    for (int e = tid; e < N_ * 32; e += 256) {
        int j = e >> 5, d = e & 31;
        Vt[d * VTS + j] = *(const short*)(qkv + (size_t)(b * N_ + j) * (3 * INNER_) + 2 * INNER_ + h * DH_ + d);
    }
    __syncthreads();

    float sc = scale[h];
    for (int qt = w; qt < 13; qt += 4) {
        int q0 = qt * 16;
        int qrow = q0 + ml;
        if (qrow > N_ - 1) qrow = N_ - 1;
        bf16x8 aq = *(const bf16x8*)(qkv + (size_t)(b * N_ + qrow) * (3 * INNER_) + h * DH_ + quad * 8);
        f32x4 accs[13];
#pragma unroll
        for (int kt = 0; kt < 13; kt++) {
            bf16x8 bk = *(const bf16x8*)(Ks + (kt * 16 + ml) * 32 + quad * 8);
            f32x4 z = {0.0f, 0.0f, 0.0f, 0.0f};
            accs[kt] = __builtin_amdgcn_mfma_f32_16x16x32_bf16(aq, bk, z, 0, 0, 0);
        }
        float rmax[4] = {-1e30f, -1e30f, -1e30f, -1e30f};
#pragma unroll
        for (int kt = 0; kt < 13; kt++) {
            int key = kt * 16 + ml;
#pragma unroll
            for (int reg = 0; reg < 4; reg++) {
                int qg = q0 + quad * 4 + reg;
                bool valid = (key < N_) && (key != qg);
                float s = valid ? accs[kt][reg] * sc : -1e30f;
                accs[kt][reg] = s;
                rmax[reg] = fmaxf(rmax[reg], s);
            }
        }
#pragma unroll
        for (int m = 1; m <= 8; m <<= 1)
#pragma unroll
            for (int reg = 0; reg < 4; reg++)
                rmax[reg] = fmaxf(rmax[reg], __shfl_xor(rmax[reg], m));
        float rsum[4] = {0.0f, 0.0f, 0.0f, 0.0f};
#pragma unroll
        for (int kt = 0; kt < 13; kt++) {
#pragma unroll
            for (int reg = 0; reg < 4; reg++) {
                float wgt = __expf(accs[kt][reg] - rmax[reg]);
                accs[kt][reg] = wgt;
                rsum[reg] += wgt;
            }
        }
#pragma unroll
        for (int m = 1; m <= 8; m <<= 1)
#pragma unroll
            for (int reg = 0; reg < 4; reg++)
                rsum[reg] += __shfl_xor(rsum[reg], m);
#pragma unroll
        for (int kt = 0; kt < 13; kt++)
#pragma unroll
            for (int reg = 0; reg < 4; reg++)
                Ps[w][(quad * 4 + reg) * PSS + kt * 16 + ml] = f2b_raw(accs[kt][reg]);
        f32x4 acco[2] = {{0.0f, 0.0f, 0.0f, 0.0f}, {0.0f, 0.0f, 0.0f, 0.0f}};
#pragma unroll
        for (int kc = 0; kc < 7; kc++) {
            bf16x8 ap2 = *(const bf16x8*)(Ps[w] + ml * PSS + kc * 32 + quad * 8);
#pragma unroll
            for (int nt = 0; nt < 2; nt++) {
                bf16x8 bv = *(const bf16x8*)(Vt + (nt * 16 + ml) * VTS + kc * 32 + quad * 8);
                acco[nt] = __builtin_amdgcn_mfma_f32_16x16x32_bf16(ap2, bv, acco[nt], 0, 0, 0);
            }
        }
#pragma unroll
        for (int reg = 0; reg < 4; reg++) {
            int qg = q0 + quad * 4 + reg;
            if (qg >= N_) continue;
            float inv = 1.0f / rsum[reg];
#pragma unroll
            for (int nt = 0; nt < 2; nt++)
                o[(size_t)(b * N_ + qg) * INNER_ + h * DH_ + nt * 16 + ml] = f2b(acco[nt][reg] * inv);
        }
    }
}

// ------------------------------------------------------------------ diagnostics (f32 out)
__global__ __launch_bounds__(256) void diag_kernel(const float* __restrict__ bufx,
                                                   float* __restrict__ outf,
                                                   int base_marker, int ran) {
    __shared__ int bad;
    if (threadIdx.x == 0) bad = 0;
    __syncthreads();
    if (ran) {
        for (int i = threadIdx.x; i < 4096; i += 256) {
            float v = bufx[i];
            if (!(fabsf(v) < 1e30f)) bad = 1;
        }
    }
    __syncthreads();
    int marker = base_marker + (bad ? 512 : 0);
    if (marker == 0) return;
    int idx = blockIdx.x * 256 + threadIdx.x;
    if (idx > 0 && idx < 64000) outf[idx] = 0.0f;
    if (idx == 0) outf[0] = (float)marker;
}

// ------------------------------------------------------------------ launch
extern "C" void kernel_launch(void* const* d_in, const int* in_sizes, int n_in,
                              void* d_out, int out_size, void* d_ws, size_t ws_size,
                              hipStream_t stream) {
    const float* img     = (const float*)d_in[0];
    const float* patch_w = (const float*)d_in[1];
    const float* patch_b = (const float*)d_in[2];
    const float* pos_emb = (const float*)d_in[3];
    const float* cls_tok = (const float*)d_in[4];
    const float* ln1_g   = (const float*)d_in[5];
    const float* ln1_b   = (const float*)d_in[6];
    const float* qkv_w   = (const float*)d_in[7];
    const float* scale   = (const float*)d_in[8];
    const float* out_w   = (const float*)d_in[9];
    const float* out_b   = (const float*)d_in[10];
    const float* ln2_g   = (const float*)d_in[11];
    const float* ln2_b   = (const float*)d_in[12];
    const float* ff_w1   = (const float*)d_in[13];
    const float* ff_b1   = (const float*)d_in[14];
    const float* ff_w2   = (const float*)d_in[15];
    const float* ff_b2   = (const float*)d_in[16];
    const float* lnf_g   = (const float*)d_in[17];
    const float* lnf_b   = (const float*)d_in[18];
    const float* head_w  = (const float*)d_in[19];
    const float* head_b  = (const float*)d_in[20];

    const size_t NEED      = 58146816;
    const size_t NEED_FAST = 101990400;
    const size_t NEED_FULL = 140722176;
    char* ws = (char*)d_ws;
    const int ROWS = B_ * N_;  // 12608
    const int GY = (ROWS + 127) / 128;  // 99

    if (ws_size < NEED) {
        diag_kernel<<<250, 256, 0, stream>>>((const float*)d_out, (float*)d_out,
                                             1024 + (int)(ws_size >> 20), 0);
        return;
    }

    float* buf_x  = (float*)ws;                    // 19,365,888 (all tiers)
    bf16*  buf_hb = (bf16*)(ws + 19365888);        //  9,682,944 (all tiers)

    if (ws_size >= NEED_FAST) {
        // ---- bf16-weight tiers (FAST / FULL) ----
        bool full = (ws_size >= NEED_FULL);
        bf16 *buf_qkv, *buf_ff, *buf_patch, *meanimg, *buf_cls;
        bf16 *wb_patch, *wb_qkv, *wb_out, *wb_ff1, *wb_ff2;
        int pchunks, fchunks;
        if (full) {
            buf_qkv  = (bf16*)(ws + 29048832);
            buf_ff   = (bf16*)(ws + 58097664);
            buf_patch= (bf16*)(ws + 29048832);
            meanimg  = (bf16*)(ws + 74006528);
            wb_patch = (bf16*)(ws + 96829440);
            wb_qkv   = (bf16*)(ws + 98205696);
            wb_out   = (bf16*)(ws + 108822528);
            wb_ff1   = (bf16*)(ws + 112361472);
            wb_ff2   = (bf16*)(ws + 126517248);
            buf_cls  = (bf16*)(ws + 140673024);
            pchunks = 1; fchunks = 1;
        } else {
            buf_qkv  = (bf16*)(ws + 29048832);
            buf_ff   = (bf16*)(ws + 29048832);
            buf_patch= (bf16*)(ws + 29048832);
            meanimg  = (bf16*)(ws + 29048832 + 22478848);
            buf_cls  = (bf16*)(ws + 58097664);
            wb_patch = (bf16*)(ws + 58146816);
            wb_qkv   = (bf16*)(ws + 59523072);
            wb_out   = (bf16*)(ws + 70139904);
            wb_ff1   = (bf16*)(ws + 73678848);
            wb_ff2   = (bf16*)(ws + 87834624);
            pchunks = 2; fchunks = 2;
        }

        wconv_kernel<<<(688128 / 4 + 255) / 256, 256, 0, stream>>>(patch_w, wb_patch, 688128 / 4);
        wconv_kernel<<<(5308416 / 4 + 255) / 256, 256, 0, stream>>>(qkv_w, wb_qkv, 5308416 / 4);
        wconv_kernel<<<(1769472 / 4 + 255) / 256, 256, 0, stream>>>(out_w, wb_out, 1769472 / 4);
        wconv_kernel<<<(7077888 / 4 + 255) / 256, 256, 0, stream>>>(ff_w1, wb_ff1, 7077888 / 4);
        wconv_kernel<<<(7077888 / 4 + 255) / 256, 256, 0, stream>>>(ff_w2, wb_ff2, 7077888 / 4);

        mean_kernel<<<(B_ * 50176 + 255) / 256, 256, 0, stream>>>(img, meanimg);
        for (int c = 0; c < pchunks; c++) {
            int bp0 = c * (12544 / pchunks);
            int nbp = 12544 / pchunks;
            patches_kernel<<<nbp, 256, 0, stream>>>(img, meanimg, buf_patch, bp0, nbp);
            mgemm8_kernel<0, bf16><<<dim3(3, (nbp + 127) / 128), 256, 0, stream>>>(
                buf_patch, wb_patch, patch_b, nullptr, buf_hb + (size_t)bp0 * DIM_, nbp, DIM_, PD_);
        }
        addpos_kernel<<<(B_ * N_ * DIM_ + 255) / 256, 256, 0, stream>>>(buf_hb, cls_tok, pos_emb, buf_x);

        for (int i = 0; i < DEPTH_; i++) {
            ln_kernel<<<ROWS / 4, 256, 0, stream>>>(buf_x, DIM_, ln1_g + i * DIM_,
                                                    ln1_b + i * DIM_, buf_hb, ROWS);
            mgemm8_kernel<0, bf16><<<dim3(9, GY), 256, 0, stream>>>(
                buf_hb, wb_qkv + (size_t)i * 3 * INNER_ * DIM_, nullptr, nullptr, buf_qkv,
                ROWS, 3 * INNER_, DIM_);
            attn_mfma_kernel<<<dim3(B_, H_), 256, 0, stream>>>(buf_qkv, scale + i * H_, buf_hb);
            mgemm8_kernel<1, float><<<dim3(3, GY), 256, 0, stream>>>(
                buf_hb, wb_out + (size_t)i * DIM_ * INNER_, out_b + i * DIM_, buf_x, buf_x,
                ROWS, DIM_, INNER_);
            ln_kernel<<<ROWS / 4, 256, 0, stream>>>(buf_x, DIM_, ln2_g + i * DIM_,
                                                    ln2_b + i * DIM_, buf_hb, ROWS);
            int base = 0;
            for (int c = 0; c < fchunks; c++) {
                int mrows = (fchunks == 1) ? ROWS : ((c == 0) ? 6336 : 6272);
                int gy = (mrows + 127) / 128;
                mgemm8_kernel<2, bf16><<<dim3(12, gy), 256, 0, stream>>>(
                    buf_hb + (size_t)base * DIM_, wb_ff1 + (size_t)i * MLP_ * DIM_,
                    ff_b1 + i * MLP_, nullptr, buf_ff, mrows, MLP_, DIM_);
                mgemm8_kernel<1, float><<<dim3(3, gy), 256, 0, stream>>>(
                    buf_ff, wb_ff2 + (size_t)i * DIM_ * MLP_, ff_b2 + i * DIM_,
                    buf_x + (size_t)base * DIM_, buf_x + (size_t)base * DIM_, mrows, DIM_, MLP_);
                base += mrows;
            }
        }

        ln_kernel<<<B_ / 4, 256, 0, stream>>>(buf_x, (long)N_ * DIM_, lnf_g, lnf_b, buf_cls, B_);
        head_kernel<<<250, 256, 0, stream>>>(buf_cls, head_w, head_b, (float*)d_out);
        diag_kernel<<<250, 256, 0, stream>>>(buf_x, (float*)d_out, 0, 1);
        return;
    }

    // ---- base tier: round-7 proven path (W f32 in-kernel convert) ----
    bf16* buf_cd   = (bf16*)(ws + 29048832);
    bf16* meanimg  = (bf16*)(ws + 29048832 + 22478848);
    bf16* buf_cls  = (bf16*)(ws + 58097664);

    mean_kernel<<<(B_ * 50176 + 255) / 256, 256, 0, stream>>>(img, meanimg);
    for (int c = 0; c < 2; c++) {
        int bp0 = c * 6272;
        patches_kernel<<<6272, 256, 0, stream>>>(img, meanimg, buf_cd, bp0, 6272);
        mgemm_kernel<0, bf16><<<dim3(DIM_ / 64, 49), 256, 0, stream>>>(
            buf_cd, patch_w, patch_b, nullptr, buf_hb + (size_t)bp0 * DIM_, 6272, DIM_, PD_);
    }
    addpos_kernel<<<(B_ * N_ * DIM_ + 255) / 256, 256, 0, stream>>>(buf_hb, cls_tok, pos_emb, buf_x);

    for (int i = 0; i < DEPTH_; i++) {
        ln_kernel<<<ROWS / 4, 256, 0, stream>>>(buf_x, DIM_, ln1_g + i * DIM_,
                                                ln1_b + i * DIM_, buf_hb, ROWS);
        mgemm_kernel<0, bf16><<<dim3((3 * INNER_) / 64, GY), 256, 0, stream>>>(
            buf_hb, qkv_w + (size_t)i * 3 * INNER_ * DIM_, nullptr, nullptr, buf_cd,
            ROWS, 3 * INNER_, DIM_);
        attn_mfma_kernel<<<dim3(B_, H_), 256, 0, stream>>>(buf_cd, scale + i * H_, buf_hb);
        mgemm_kernel<1, float><<<dim3(DIM_ / 64, GY), 256, 0, stream>>>(
            buf_hb, out_w + (size_t)i * DIM_ * INNER_, out_b + i * DIM_, buf_x, buf_x,
            ROWS, DIM_, INNER_);
        ln_kernel<<<ROWS / 4, 256, 0, stream>>>(buf_x, DIM_, ln2_g + i * DIM_,
                                                ln2_b + i * DIM_, buf_hb, ROWS);
        int base = 0;
        for (int c = 0; c < 2; c++) {
            int mrows = (c == 0) ? 6336 : 6272;
            int gy = (mrows + 127) / 128;
            mgemm_kernel<2, bf16><<<dim3(MLP_ / 64, gy), 256, 0, stream>>>(
                buf_hb + (size_t)base * DIM_, ff_w1 + (size_t)i * MLP_ * DIM_,
                ff_b1 + i * MLP_, nullptr, buf_cd, mrows, MLP_, DIM_);
            mgemm_kernel<1, float><<<dim3(DIM_ / 64, gy), 256, 0, stream>>>(
                buf_cd, ff_w2 + (size_t)i * DIM_ * MLP_, ff_b2 + i * DIM_,
                buf_x + (size_t)base * DIM_, buf_x + (size_t)base * DIM_, mrows, DIM_, MLP_);
            base += mrows;
        }
    }

    ln_kernel<<<B_ / 4, 256, 0, stream>>>(buf_x, (long)N_ * DIM_, lnf_g, lnf_b, buf_cls, B_);
    head_kernel<<<250, 256, 0, stream>>>(buf_cls, head_w, head_b, (float*)d_out);
    diag_kernel<<<250, 256, 0, stream>>>(buf_x, (float*)d_out, 0, 1);
}

// Round 7
// 2132.148 us; speedup vs baseline: 1.8022x; 1.0823x over previous
//
#include <hip/hip_runtime.h>
#include <hip/hip_bf16.h>

// Model constants
#define B_ 64
#define IMG_ 224
#define P_ 16
#define G_ 14
#define NP_ 196
#define N_ 197
#define DIM_ 384
#define DEPTH_ 12
#define H_ 12
#define DH_ 32
#define INNER_ 384
#define MLP_ 1536
#define NCLS_ 1000
#define PD_ 1792
#define EPS_ 1e-5f

typedef __hip_bfloat16 bf16;
using bf16x8 = __attribute__((ext_vector_type(8))) short;   // 8 bf16 (4 VGPRs)
using f32x4  = __attribute__((ext_vector_type(4))) float;   // MFMA acc

typedef __attribute__((address_space(1))) const void gas_void;
typedef __attribute__((address_space(3))) void las_void;

__device__ __forceinline__ float b2f(bf16 x) { return __bfloat162float(x); }
__device__ __forceinline__ bf16 f2b(float x) { return __float2bfloat16(x); }
__device__ __forceinline__ short f2b_raw(float f) {
    unsigned x = __float_as_uint(f);
    unsigned r = (x + 0x7FFFu + ((x >> 16) & 1u)) >> 16;
    return (short)r;
}
// raw workgroup barrier WITHOUT implicit vmcnt(0) drain
__device__ __forceinline__ void barrier_raw() {
    asm volatile("s_barrier" ::: "memory");
}
__device__ __forceinline__ void waitcnt_vm8() {
    asm volatile("s_waitcnt vmcnt(8)" ::: "memory");
}
__device__ __forceinline__ void waitcnt_vm3() {
    asm volatile("s_waitcnt vmcnt(3)" ::: "memory");
}
__device__ __forceinline__ void waitcnt_vm0() {
    asm volatile("s_waitcnt vmcnt(0)" ::: "memory");
}
// rule 18: lgkmcnt(0) drain + scheduling fence so MFMAs can't hoist above it
__device__ __forceinline__ void lgkm0_fence() {
    asm volatile("s_waitcnt lgkmcnt(0)" ::: "memory");
    __builtin_amdgcn_sched_barrier(0);
}

// ---------------------------------------------------------------- weight f32->bf16
__global__ __launch_bounds__(256) void wconv_kernel(const float* __restrict__ src,
                                                    bf16* __restrict__ dst, int n4) {
    int i = blockIdx.x * 256 + threadIdx.x;
    if (i >= n4) return;
    float4 v = ((const float4*)src)[i];
    short4 o;
    o.x = f2b_raw(v.x); o.y = f2b_raw(v.y);
    o.z = f2b_raw(v.z); o.w = f2b_raw(v.w);
    ((short4*)dst)[i] = o;
}

// ---------------------------------------------------------------- mean image (bf16)
__global__ __launch_bounds__(256) void mean_kernel(const float* __restrict__ img,
                                                   bf16* __restrict__ meanimg) {
    int idx = blockIdx.x * 256 + threadIdx.x;
    if (idx >= B_ * 50176) return;
    int b = idx / 50176;
    int yx = idx - b * 50176;
    const float* p = img + (size_t)b * 3 * 50176 + yx;
    meanimg[idx] = f2b((p[0] + p[50176] + p[100352]) * (1.0f / 3.0f));
}

// ------------------------------------------------------------- patch matrix (chunked)
__global__ __launch_bounds__(256) void patches_kernel(const float* __restrict__ img,
                                                      const bf16* __restrict__ meanimg,
                                                      bf16* __restrict__ patches,
                                                      int bp0, int nbp) {
    int idx = blockIdx.x * 256 + threadIdx.x;
    if (idx >= nbp * 256) return;
    int pix = idx & 255;
    int px = pix & 15, py = pix >> 4;
    int lbp = idx >> 8;
    int bp = bp0 + lbp;
    int p = bp % NP_;
    int b = bp / NP_;
    int gy = p / G_, gx = p - gy * G_;
    int y = gy * P_ + py, x = gx * P_ + px;
    const float* ib = img + (size_t)b * 3 * 50176 + y * 224 + x;
    bf16* out = patches + (size_t)lbp * PD_ + pix * 7;
    out[0] = f2b(ib[0]);
    out[1] = f2b(ib[50176]);
    out[2] = f2b(ib[100352]);
    const bf16* mb = meanimg + (size_t)b * 50176;
    out[3] = (x >= 8)  ? mb[y * 224 + x - 8]   : f2b(0.0f);   // l2
    out[4] = (x < 216) ? mb[y * 224 + x + 8]   : f2b(0.0f);   // r2
    out[5] = (y >= 8)  ? mb[(y - 8) * 224 + x] : f2b(0.0f);   // t2
    out[6] = (y < 216) ? mb[(y + 8) * 224 + x] : f2b(0.0f);   // b2
}

// --------------------------------------------------- cls + pos_emb assembly
__global__ __launch_bounds__(256) void addpos_kernel(const bf16* __restrict__ pe,
                                                     const float* __restrict__ cls_tok,
                                                     const float* __restrict__ pos_emb,
                                                     float* __restrict__ x) {
    int idx = blockIdx.x * 256 + threadIdx.x;
    if (idx >= B_ * N_ * DIM_) return;
    int c = idx % DIM_;
    int r = idx / DIM_;
    int t = r % N_;
    int b = r / N_;
    float v = (t == 0) ? cls_tok[c]
                       : b2f(pe[((size_t)(b * NP_ + t - 1)) * DIM_ + c]);
    x[idx] = v + pos_emb[t * DIM_ + c];
}

// ------------------------------------------------------------------ layernorm
__global__ __launch_bounds__(256) void ln_kernel(const float* __restrict__ in,
                                                 long in_stride,
                                                 const float* __restrict__ g,
                                                 const float* __restrict__ bb,
                                                 bf16* __restrict__ out, int rows) {
    int wave = threadIdx.x >> 6;
    int lane = threadIdx.x & 63;
    int row = blockIdx.x * 4 + wave;
    if (row >= rows) return;
    const float* p = in + (size_t)row * in_stride;
    float v[6];
    float s = 0.0f, s2 = 0.0f;
#pragma unroll
    for (int i = 0; i < 6; i++) {
        v[i] = p[lane + 64 * i];
        s += v[i];
        s2 += v[i] * v[i];
    }
#pragma unroll
    for (int m = 32; m >= 1; m >>= 1) {
        s += __shfl_xor(s, m);
        s2 += __shfl_xor(s2, m);
    }
    float mu = s * (1.0f / 384.0f);
    float var = s2 * (1.0f / 384.0f) - mu * mu;
    var = fmaxf(var, 0.0f);
    float inv = rsqrtf(var + EPS_);
    bf16* q = out + (size_t)row * DIM_;
#pragma unroll
    for (int i = 0; i < 6; i++) {
        int c = lane + 64 * i;
        q[c] = f2b((v[i] - mu) * inv * g[c] + bb[c]);
    }
}

// ------------------------------------------------------------------ head GEMM (wave/col)
__global__ __launch_bounds__(256) void head_kernel(const bf16* __restrict__ cls,
                                                   const float* __restrict__ W,
                                                   const float* __restrict__ bias,
                                                   float* __restrict__ out) {
    int wv = threadIdx.x >> 6, lane = threadIdx.x & 63;
    int col = blockIdx.x * 4 + wv;
    if (col >= NCLS_) return;
    const float* wp = W + (size_t)col * DIM_;
    float wreg[6];
#pragma unroll
    for (int i = 0; i < 6; i++) wreg[i] = wp[i * 64 + lane];
    float hb = bias[col];
    float res = 0.0f;
    for (int r = 0; r < 64; r++) {
        const bf16* ar = cls + r * DIM_;
        float s = 0.0f;
#pragma unroll
        for (int i = 0; i < 6; i++) s += b2f(ar[i * 64 + lane]) * wreg[i];
#pragma unroll
        for (int m = 32; m >= 1; m >>= 1) s += __shfl_xor(s, m);
        if (lane == r) res = s + hb;
    }
    out[(size_t)lane * NCLS_ + col] = res;
}

// ------------------------------------------------------------------ MFMA GEMM v5 (phase-split)
// (r3 proven-best kernel, unchanged.) BM=128 BN=128 BK=64, db2 LDS (64 KB).
// MODE 0: bias. 1: bias+res(f32). 2: bias+exact GELU. N%128==0, K%64==0, K>=128.
template <int MODE, typename OutT>
__global__ __launch_bounds__(256) void mgemm5_kernel(const bf16* __restrict__ A,
                                                     const bf16* __restrict__ W,
                                                     const float* __restrict__ bias,
                                                     const float* __restrict__ res,
                                                     OutT* __restrict__ C,
                                                     int M, int N, int K) {
    __shared__ __align__(16) short lds_a[2][128 * 64];   // 2 x 16 KB
    __shared__ __align__(16) short lds_b[2][128 * 64];   // 2 x 16 KB
    int tid = threadIdx.x;
    int wv = tid >> 6, lane = tid & 63;
    int ml = lane & 15, quad = lane >> 4;

    // ---- XCD-aware bijective remap ----
    unsigned gx = gridDim.x;
    unsigned nwg = gx * gridDim.y;
    unsigned lid = blockIdx.y * gx + blockIdx.x;
    unsigned qc = nwg >> 3, rc = nwg & 7u;
    unsigned xcd = lid & 7u, loc = lid >> 3;
    unsigned nlid = (xcd < rc ? xcd * (qc + 1u)
                              : rc * (qc + 1u) + (xcd - rc) * qc) + loc;
    unsigned bx = nlid % gx, by = nlid / gx;
    int rowBase = by * 128, colBase = bx * 128;

    int l8 = lane >> 3;                 // row within 8-row group
    int c8 = lane & 7;                  // LDS chunk slot
    int swsrc = ((c8 ^ l8) << 3);       // source chunk offset (shorts)
    const bf16* aS[4];
    const bf16* bS[4];
#pragma unroll
    for (int j = 0; j < 4; j++) {
        int lr = wv * 32 + j * 8 + l8;          // local row 0..127
        int gr = rowBase + lr; if (gr >= M) gr = M - 1;
        aS[j] = A + (size_t)gr * K + swsrc;
        bS[j] = W + (size_t)(colBase + lr) * K + swsrc;
    }
    short* ldsA0 = &lds_a[0][0];
    short* ldsB0 = &lds_b[0][0];
    int dstOff = (wv * 32) * 64;                // shorts; +j*512 per instr

#define ISSUE_TILE5(bufi, t)                                                                        \
    do {                                                                                            \
        _Pragma("unroll")                                                                           \
        for (int j = 0; j < 4; j++) {                                                               \
            __builtin_amdgcn_global_load_lds((gas_void*)(aS[j] + (size_t)(t) * 64),                 \
                (las_void*)(ldsA0 + (bufi) * 8192 + dstOff + j * 512), 16, 0, 0);                   \
            __builtin_amdgcn_global_load_lds((gas_void*)(bS[j] + (size_t)(t) * 64),                 \
                (las_void*)(ldsB0 + (bufi) * 8192 + dstOff + j * 512), 16, 0, 0);                   \
        }                                                                                           \
    } while (0)

    int wr = (wv >> 1) * 64, wc = (wv & 1) * 64;
    int sw0 = ((quad ^ (ml & 7)) << 3);
    int sw1 = (((4 + quad) ^ (ml & 7)) << 3);
    f32x4 acc[4][4] = {};
    int NT = K >> 6;

    ISSUE_TILE5(0, 0);
    ISSUE_TILE5(1, 1);

    for (int t = 0; t < NT; t++) {
        if (t + 1 < NT) waitcnt_vm8();
        else            waitcnt_vm0();
        barrier_raw();
        int cb = t & 1;
        const short* pa = &lds_a[cb][0];
        const short* pb = &lds_b[cb][0];

        bf16x8 af0[4], bf0[4];
#pragma unroll
        for (int rg = 0; rg < 4; rg++)
            af0[rg] = *(const bf16x8*)(pa + (wr + rg * 16 + ml) * 64 + sw0);
#pragma unroll
        for (int cg = 0; cg < 4; cg++)
            bf0[cg] = *(const bf16x8*)(pb + (wc + cg * 16 + ml) * 64 + sw0);
        lgkm0_fence();
        __builtin_amdgcn_s_setprio(1);
#pragma unroll
        for (int rg = 0; rg < 4; rg++)
#pragma unroll
            for (int cg = 0; cg < 4; cg++)
                acc[rg][cg] = __builtin_amdgcn_mfma_f32_16x16x32_bf16(af0[rg], bf0[cg], acc[rg][cg], 0, 0, 0);
        __builtin_amdgcn_s_setprio(0);

        bf16x8 af1[4], bf1[4];
#pragma unroll
        for (int rg = 0; rg < 4; rg++)
            af1[rg] = *(const bf16x8*)(pa + (wr + rg * 16 + ml) * 64 + sw1);
#pragma unroll
        for (int cg = 0; cg < 4; cg++)
            bf1[cg] = *(const bf16x8*)(pb + (wc + cg * 16 + ml) * 64 + sw1);
        lgkm0_fence();
        __builtin_amdgcn_s_setprio(1);
#pragma unroll
        for (int rg = 0; rg < 4; rg++)
#pragma unroll
            for (int cg = 0; cg < 4; cg++)
                acc[rg][cg] = __builtin_amdgcn_mfma_f32_16x16x32_bf16(af1[rg], bf1[cg], acc[rg][cg], 0, 0, 0);
        __builtin_amdgcn_s_setprio(0);

        barrier_raw();
        if (t + 2 < NT) ISSUE_TILE5(cb, t + 2);
    }
#undef ISSUE_TILE5

    float bval[4];
#pragma unroll
    for (int cg = 0; cg < 4; cg++)
        bval[cg] = bias ? bias[colBase + wc + cg * 16 + ml] : 0.0f;

#pragma unroll
    for (int rg = 0; rg < 4; rg++) {
#pragma unroll
        for (int reg = 0; reg < 4; reg++) {
            int r = rowBase + wr + rg * 16 + quad * 4 + reg;
            if (r >= M) continue;
            size_t ro = (size_t)r * N;
#pragma unroll
            for (int cg = 0; cg < 4; cg++) {
                int c = colBase + wc + cg * 16 + ml;
                float v = acc[rg][cg][reg] + bval[cg];
                if constexpr (MODE == 1) v += res[ro + c];
                if constexpr (MODE == 2) v = 0.5f * v * (1.0f + erff(v * 0.70710678118f));
                C[ro + c] = (OutT)v;
            }
        }
    }
}

// ------------------------------------------------------------------ MFMA GEMM v9 (256x128 tile)
// C[M,N] = A[M,K] @ W[N,K]^T, both bf16. BM=256 BN=128 BK=32, db2 (48 KB LDS),
// 512 threads (8 waves, 4Mx2N, per-wave 64x64 acc[4][4] -- same regs as 128-tile).
// Rationale (r1-r6): GEMM time == staged bytes / ~5.2 TB/s regardless of staging
// mechanism or schedule; the only remaining lever is BYTES. BM=256 cuts staged
// volume 24% for the M=12608 GEMMs (ff1: 233->177 MB, qkv: 174->133 MB) while
// 48 KB LDS keeps 3 blocks/CU (24 waves). Staging map is linear in 16B-chunk id
// (dst = chunk*16B), satisfying global_load_lds' wave-uniform-base + lane*16
// constraint. Per-output K-order identical to mgemm3/5 -> same numerics.
// Use only where grid >= 256 blocks (ff1, qkv). N%128==0, K%32==0, K>=96.
template <int MODE, typename OutT>
__global__ __launch_bounds__(512) void mgemm9_kernel(const bf16* __restrict__ A,
                                                     const bf16* __restrict__ W,
                                                     const float* __restrict__ bias,
                                                     const float* __restrict__ res,
                                                     OutT* __restrict__ C,
                                                     int M, int N, int K) {
    __shared__ __align__(16) short lds_a[2][256 * 32];   // 2 x 16 KB
    __shared__ __align__(16) short lds_b[2][128 * 32];   // 2 x 8 KB
    int tid = threadIdx.x;                // 0..511
    int wv = tid >> 6, lane = tid & 63;   // wv 0..7
    int ml = lane & 15, quad = lane >> 4;

    // ---- XCD-aware bijective remap ----
    unsigned gx = gridDim.x;
    unsigned nwg = gx * gridDim.y;
    unsigned lid = blockIdx.y * gx + blockIdx.x;
    unsigned qc = nwg >> 3, rc = nwg & 7u;
    unsigned xcd = lid & 7u, loc = lid >> 3;
    unsigned nlid = (xcd < rc ? xcd * (qc + 1u)
                              : rc * (qc + 1u) + (xcd - rc) * qc) + loc;
    unsigned bx = nlid % gx, by = nlid / gx;
    int rowBase = by * 256, colBase = bx * 128;

    // staging: A tile = 1024 chunks of 16 B (row = q>>2, ch = q&3); thread t
    // owns chunks t and t+512. B tile = 512 chunks; thread t owns chunk t.
    // LDS dst offset = chunk*16 B (linear) -> per-wave base + lane*16. ✓
    int raA0 = tid >> 2,        caA0 = (tid & 3) * 8;          // chunk t
    int raA1 = (tid + 512) >> 2, caA1 = (tid & 3) * 8;         // chunk t+512
    int raB  = tid >> 2,        caB  = (tid & 3) * 8;
    int gA0 = rowBase + raA0; if (gA0 >= M) gA0 = M - 1;
    int gA1 = rowBase + raA1; if (gA1 >= M) gA1 = M - 1;
    const bf16* aS0 = A + (size_t)gA0 * K + caA0;
    const bf16* aS1 = A + (size_t)gA1 * K + caA1;
    const bf16* bS  = W + (size_t)(colBase + raB) * K + caB;
    short* ldsA0 = &lds_a[0][0];
    short* ldsB0 = &lds_b[0][0];
    int dA0 = tid * 8;             // shorts (chunk t)
    int dA1 = 4096 + tid * 8;      // shorts (chunk t+512)
    int dB  = tid * 8;

#define ISSUE9(bufi, k0)                                                                              \
    do {                                                                                              \
        __builtin_amdgcn_global_load_lds((gas_void*)(aS0 + (k0)), (las_void*)(ldsA0 + (bufi) * 8192 + dA0), 16, 0, 0); \
        __builtin_amdgcn_global_load_lds((gas_void*)(aS1 + (k0)), (las_void*)(ldsA0 + (bufi) * 8192 + dA1), 16, 0, 0); \
        __builtin_amdgcn_global_load_lds((gas_void*)(bS  + (k0)), (las_void*)(ldsB0 + (bufi) * 4096 + dB),  16, 0, 0); \
    } while (0)

    // wave -> 64x64 output sub-tile: 4 rows of waves x 2 cols
    int wr = (wv >> 1) * 64, wc = (wv & 1) * 64;
    f32x4 acc[4][4] = {};
    int NK = K >> 5;

    ISSUE9(0, 0);
    ISSUE9(1, 32);

    for (int k = 0; k < NK; k++) {
        if (k + 1 < NK) waitcnt_vm3();   // tile k done; k+1 (3 instr) in flight
        else            waitcnt_vm0();
        barrier_raw();
        int cb = k & 1;
        const short* pa = &lds_a[cb][0];
        const short* pb = &lds_b[cb][0];
        bf16x8 af[4], bfr[4];
#pragma unroll
        for (int rg = 0; rg < 4; rg++)
            af[rg] = *(const bf16x8*)(pa + (wr + rg * 16 + ml) * 32 + quad * 8);
#pragma unroll
        for (int cg = 0; cg < 4; cg++)
            bfr[cg] = *(const bf16x8*)(pb + (wc + cg * 16 + ml) * 32 + quad * 8);
#pragma unroll
        for (int rg = 0; rg < 4; rg++)
#pragma unroll
            for (int cg = 0; cg < 4; cg++)
                acc[rg][cg] = __builtin_amdgcn_mfma_f32_16x16x32_bf16(af[rg], bfr[cg], acc[rg][cg], 0, 0, 0);
        barrier_raw();
        if (k + 2 < NK) ISSUE9(cb, (k + 2) * 32);
    }
#undef ISSUE9

    float bval[4];
#pragma unroll
    for (int cg = 0; cg < 4; cg++)
        bval[cg] = bias ? bias[colBase + wc + cg * 16 + ml] : 0.0f;

#pragma unroll
    for (int rg = 0; rg < 4; rg++) {
#pragma unroll
        for (int reg = 0; reg < 4; reg++) {
            int r = rowBase + wr + rg * 16 + quad * 4 + reg;
            if (r >= M) continue;
            size_t ro = (size_t)r * N;
#pragma unroll
            for (int cg = 0; cg < 4; cg++) {
                int c = colBase + wc + cg * 16 + ml;
                float v = acc[rg][cg][reg] + bval[cg];
                if constexpr (MODE == 1) v += res[ro + c];
                if constexpr (MODE == 2) v = 0.5f * v * (1.0f + erff(v * 0.70710678118f));
                C[ro + c] = (OutT)v;
            }
        }
    }
}

// ------------------------------------------------------------------ MFMA GEMM v1 (base tier, W f32)
template <int MODE, typename OutT>
__global__ __launch_bounds__(256) void mgemm_kernel(const bf16* __restrict__ A,
                                                    const float* __restrict__ W,
                                                    const float* __restrict__ bias,
                                                    const float* __restrict__ res,
                                                    OutT* __restrict__ C,
                                                    int M, int N, int K) {
    __shared__ __align__(16) short lds_a[128 * 32];
    __shared__ __align__(16) short lds_b[64 * 32];
    int tid = threadIdx.x;
    int rowBase = blockIdx.y * 128;
    int colBase = blockIdx.x * 64;
    int w = tid >> 6, lane = tid & 63;
    int ml = lane & 15, kseg = lane >> 4;

    int ar = tid >> 1;
    int ah = (tid & 1) * 16;
    int agr = rowBase + ar;
    if (agr > M - 1) agr = M - 1;
    const float4* asrc_base = (const float4*)(A + (size_t)agr * K + ah);
    int br = tid >> 2;
    int bs = (tid & 3) * 8;
    const float4* wsrc_base = (const float4*)(W + (size_t)(colBase + br) * K + bs);

    f32x4 acc[2][4] = {};

    for (int k0 = 0; k0 < K; k0 += 32) {
        const float4* asrc = (const float4*)((const bf16*)asrc_base + k0);
        float4 av0 = asrc[0];
        float4 av1 = asrc[1];
        const float4* wsrc = (const float4*)((const float*)wsrc_base + k0);
        float4 w0 = wsrc[0];
        float4 w1 = wsrc[1];
        bf16x8 wb;
        wb[0] = f2b_raw(w0.x); wb[1] = f2b_raw(w0.y);
        wb[2] = f2b_raw(w0.z); wb[3] = f2b_raw(w0.w);
        wb[4] = f2b_raw(w1.x); wb[5] = f2b_raw(w1.y);
        wb[6] = f2b_raw(w1.z); wb[7] = f2b_raw(w1.w);
        __syncthreads();
        *(float4*)(lds_a + ar * 32 + ah) = av0;
        *(float4*)(lds_a + ar * 32 + ah + 8) = av1;
        *(bf16x8*)(lds_b + br * 32 + bs) = wb;
        __syncthreads();
        bf16x8 af0 = *(const bf16x8*)(lds_a + (w * 32 + ml) * 32 + kseg * 8);
        bf16x8 af1 = *(const bf16x8*)(lds_a + (w * 32 + 16 + ml) * 32 + kseg * 8);
#pragma unroll
        for (int ct = 0; ct < 4; ct++) {
            bf16x8 bf_ = *(const bf16x8*)(lds_b + (ct * 16 + ml) * 32 + kseg * 8);
            acc[0][ct] = __builtin_amdgcn_mfma_f32_16x16x32_bf16(af0, bf_, acc[0][ct], 0, 0, 0);
            acc[1][ct] = __builtin_amdgcn_mfma_f32_16x16x32_bf16(af1, bf_, acc[1][ct], 0, 0, 0);
        }
    }

    float bval[4];
#pragma unroll
    for (int ct = 0; ct < 4; ct++)
        bval[ct] = bias ? bias[colBase + ct * 16 + ml] : 0.0f;

#pragma unroll
    for (int rt = 0; rt < 2; rt++) {
#pragma unroll
        for (int reg = 0; reg < 4; reg++) {
            int r = rowBase + w * 32 + rt * 16 + kseg * 4 + reg;
            if (r >= M) continue;
            size_t ro = (size_t)r * N;
#pragma unroll
            for (int ct = 0; ct < 4; ct++) {
                int c = colBase + ct * 16 + ml;
                float v = acc[rt][ct][reg] + bval[ct];
                if constexpr (MODE == 1) v += res[ro + c];
                if constexpr (MODE == 2) v = 0.5f * v * (1.0f + erff(v * 0.70710678118f));
                C[ro + c] = (OutT)v;
            }
        }
    }
}

// ------------------------------------------------------------------ MFMA attention
#define AKR 208
#define VTS 232
#define PSS 232
__global__ __launch_bounds__(256) void attn_mfma_kernel(const bf16* __restrict__ qkv,
                                                        const float* __restrict__ scale,
                                                        bf16* __restrict__ o) {
    __shared__ __align__(16) short Ks[AKR * 32];
    __shared__ __align__(16) short Vt[32 * VTS];
    __shared__ __align__(16) short Ps[4][16 * PSS];
    int b = blockIdx.x, h = blockIdx.y;
    int tid = threadIdx.x;
    int w = tid >> 6, lane = tid & 63;
    int ml = lane & 15, quad = lane >> 4;

    for (int i = tid; i < 32 * VTS / 2; i += 256) ((int*)Vt)[i] = 0;
    for (int e = lane; e < 16 * 16; e += 64) {
        int r = e >> 4, c = e & 15;
        Ps[w][r * PSS + 208 + c] = 0;
    }
    __syncthreads();
    for (int e = tid; e < AKR * 4; e += 256) {
        int row = e >> 2, seg = e & 3;
        float4 v = {0.0f, 0.0f, 0.0f, 0.0f};
        if (row < N_)
            v = *(const float4*)(qkv + (size_t)(b * N_ + row) * (3 * INNER_) + INNER_ + h * DH_ + seg * 8);
        *(float4*)(Ks + row * 32 + seg * 8) = v;
    }
    for (int e = tid; e < N_ * 32; e += 256) {
        int j = e >> 5, d = e & 31;
        Vt[d * VTS + j] = *(const short*)(qkv + (size_t)(b * N_ + j) * (3 * INNER_) + 2 * INNER_ + h * DH_ + d);
    }
    __syncthreads();

    float sc = scale[h];
    for (int qt = w; qt < 13; qt += 4) {
        int q0 = qt * 16;
        int qrow = q0 + ml;
        if (qrow > N_ - 1) qrow = N_ - 1;
        bf16x8 aq = *(const bf16x8*)(qkv + (size_t)(b * N_ + qrow) * (3 * INNER_) + h * DH_ + quad * 8);
        f32x4 accs[13];
#pragma unroll
        for (int kt = 0; kt < 13; kt++) {
            bf16x8 bk = *(const bf16x8*)(Ks + (kt * 16 + ml) * 32 + quad * 8);
            f32x4 z = {0.0f, 0.0f, 0.0f, 0.0f};
            accs[kt] = __builtin_amdgcn_mfma_f32_16x16x32_bf16(aq, bk, z, 0, 0, 0);
        }
        float rmax[4] = {-1e30f, -1e30f, -1e30f, -1e30f};
#pragma unroll
        for (int kt = 0; kt < 13; kt++) {
            int key = kt * 16 + ml;
#pragma unroll
            for (int reg = 0; reg < 4; reg++) {
                int qg = q0 + quad * 4 + reg;
                bool valid = (key < N_) && (key != qg);
                float s = valid ? accs[kt][reg] * sc : -1e30f;
                accs[kt][reg] = s;
                rmax[reg] = fmaxf(rmax[reg], s);
            }
        }
#pragma unroll
        for (int m = 1; m <= 8; m <<= 1)
#pragma unroll
            for (int reg = 0; reg < 4; reg++)
                rmax[reg] = fmaxf(rmax[reg], __shfl_xor(rmax[reg], m));
        float rsum[4] = {0.0f, 0.0f, 0.0f, 0.0f};
#pragma unroll
        for (int kt = 0; kt < 13; kt++) {
#pragma unroll
            for (int reg = 0; reg < 4; reg++) {
                float wgt = __expf(accs[kt][reg] - rmax[reg]);
                accs[kt][reg] = wgt;
                rsum[reg] += wgt;
            }
        }
#pragma unroll
        for (int m = 1; m <= 8; m <<= 1)
#pragma unroll
            for (int reg = 0; reg < 4; reg++)
                rsum[reg] += __shfl_xor(rsum[reg], m);
#pragma unroll
        for (int kt = 0; kt < 13; kt++)
#pragma unroll
            for (int reg = 0; reg < 4; reg++)
                Ps[w][(quad * 4 + reg) * PSS + kt * 16 + ml] = f2b_raw(accs[kt][reg]);
        f32x4 acco[2] = {{0.0f, 0.0f, 0.0f, 0.0f}, {0.0f, 0.0f, 0.0f, 0.0f}};
#pragma unroll
        for (int kc = 0; kc < 7; kc++) {
            bf16x8 ap2 = *(const bf16x8*)(Ps[w] + ml * PSS + kc * 32 + quad * 8);
#pragma unroll
            for (int nt = 0; nt < 2; nt++) {
                bf16x8 bv = *(const bf16x8*)(Vt + (nt * 16 + ml) * VTS + kc * 32 + quad * 8);
                acco[nt] = __builtin_amdgcn_mfma_f32_16x16x32_bf16(ap2, bv, acco[nt], 0, 0, 0);
            }
        }
#pragma unroll
        for (int reg = 0; reg < 4; reg++) {
            int qg = q0 + quad * 4 + reg;
            if (qg >= N_) continue;
            float inv = 1.0f / rsum[reg];
#pragma unroll
            for (int nt = 0; nt < 2; nt++)
                o[(size_t)(b * N_ + qg) * INNER_ + h * DH_ + nt * 16 + ml] = f2b(acco[nt][reg] * inv);
        }
    }
}

// ------------------------------------------------------------------ diagnostics (f32 out)
__global__ __launch_bounds__(256) void diag_kernel(const float* __restrict__ bufx,
                                                   float* __restrict__ outf,
                                                   int base_marker, int ran) {
    __shared__ int bad;
    if (threadIdx.x == 0) bad = 0;
    __syncthreads();
    if (ran) {
        for (int i = threadIdx.x; i < 4096; i += 256) {
            float v = bufx[i];
            if (!(fabsf(v) < 1e30f)) bad = 1;
        }
    }
    __syncthreads();
    int marker = base_marker + (bad ? 512 : 0);
    if (marker == 0) return;
    int idx = blockIdx.x * 256 + threadIdx.x;
    if (idx > 0 && idx < 64000) outf[idx] = 0.0f;
    if (idx == 0) outf[0] = (float)marker;
}

// ------------------------------------------------------------------ launch
extern "C" void kernel_launch(void* const* d_in, const int* in_sizes, int n_in,
                              void* d_out, int out_size, void* d_ws, size_t ws_size,
                              hipStream_t stream) {
    const float* img     = (const float*)d_in[0];
    const float* patch_w = (const float*)d_in[1];
    const float* patch_b = (const float*)d_in[2];
    const float* pos_emb = (const float*)d_in[3];
    const float* cls_tok = (const float*)d_in[4];
    const float* ln1_g   = (const float*)d_in[5];
    const float* ln1_b   = (const float*)d_in[6];
    const float* qkv_w   = (const float*)d_in[7];
    const float* scale   = (const float*)d_in[8];
    const float* out_w   = (const float*)d_in[9];
    const float* out_b   = (const float*)d_in[10];
    const float* ln2_g   = (const float*)d_in[11];
    const float* ln2_b   = (const float*)d_in[12];
    const float* ff_w1   = (const float*)d_in[13];
    const float* ff_b1   = (const float*)d_in[14];
    const float* ff_w2   = (const float*)d_in[15];
    const float* ff_b2   = (const float*)d_in[16];
    const float* lnf_g   = (const float*)d_in[17];
    const float* lnf_b   = (const float*)d_in[18];
    const float* head_w  = (const float*)d_in[19];
    const float* head_b  = (const float*)d_in[20];

    const size_t NEED      = 58146816;
    const size_t NEED_FAST = 101990400;
    const size_t NEED_FULL = 140722176;
    char* ws = (char*)d_ws;
    const int ROWS = B_ * N_;  // 12608
    const int GY = (ROWS + 127) / 128;   // 99   (128-row tiles)
    const int GY2 = (ROWS + 255) / 256;  // 50   (256-row tiles)

    if (ws_size < NEED) {
        diag_kernel<<<250, 256, 0, stream>>>((const float*)d_out, (float*)d_out,
                                             1024 + (int)(ws_size >> 20), 0);
        return;
    }

    float* buf_x  = (float*)ws;                    // 19,365,888 (all tiers)
    bf16*  buf_hb = (bf16*)(ws + 19365888);        //  9,682,944 (all tiers)

    if (ws_size >= NEED_FAST) {
        // ---- bf16-weight tiers (FAST / FULL) ----
        bool full = (ws_size >= NEED_FULL);
        bf16 *buf_qkv, *buf_ff, *buf_patch, *meanimg, *buf_cls;
        bf16 *wb_patch, *wb_qkv, *wb_out, *wb_ff1, *wb_ff2;
        int pchunks, fchunks;
        if (full) {
            buf_qkv  = (bf16*)(ws + 29048832);
            buf_ff   = (bf16*)(ws + 58097664);
            buf_patch= (bf16*)(ws + 29048832);
            meanimg  = (bf16*)(ws + 74006528);
            wb_patch = (bf16*)(ws + 96829440);
            wb_qkv   = (bf16*)(ws + 98205696);
            wb_out   = (bf16*)(ws + 108822528);
            wb_ff1   = (bf16*)(ws + 112361472);
            wb_ff2   = (bf16*)(ws + 126517248);
            buf_cls  = (bf16*)(ws + 140673024);
            pchunks = 1; fchunks = 1;
        } else {
            buf_qkv  = (bf16*)(ws + 29048832);
            buf_ff   = (bf16*)(ws + 29048832);
            buf_patch= (bf16*)(ws + 29048832);
            meanimg  = (bf16*)(ws + 29048832 + 22478848);
            buf_cls  = (bf16*)(ws + 58097664);
            wb_patch = (bf16*)(ws + 58146816);
            wb_qkv   = (bf16*)(ws + 59523072);
            wb_out   = (bf16*)(ws + 70139904);
            wb_ff1   = (bf16*)(ws + 73678848);
            wb_ff2   = (bf16*)(ws + 87834624);
            pchunks = 2; fchunks = 2;
        }

        wconv_kernel<<<(688128 / 4 + 255) / 256, 256, 0, stream>>>(patch_w, wb_patch, 688128 / 4);
        wconv_kernel<<<(5308416 / 4 + 255) / 256, 256, 0, stream>>>(qkv_w, wb_qkv, 5308416 / 4);
        wconv_kernel<<<(1769472 / 4 + 255) / 256, 256, 0, stream>>>(out_w, wb_out, 1769472 / 4);
        wconv_kernel<<<(7077888 / 4 + 255) / 256, 256, 0, stream>>>(ff_w1, wb_ff1, 7077888 / 4);
        wconv_kernel<<<(7077888 / 4 + 255) / 256, 256, 0, stream>>>(ff_w2, wb_ff2, 7077888 / 4);

        mean_kernel<<<(B_ * 50176 + 255) / 256, 256, 0, stream>>>(img, meanimg);
        for (int c = 0; c < pchunks; c++) {
            int bp0 = c * (12544 / pchunks);
            int nbp = 12544 / pchunks;
            patches_kernel<<<nbp, 256, 0, stream>>>(img, meanimg, buf_patch, bp0, nbp);
            mgemm5_kernel<0, bf16><<<dim3(3, (nbp + 127) / 128), 256, 0, stream>>>(
                buf_patch, wb_patch, patch_b, nullptr, buf_hb + (size_t)bp0 * DIM_, nbp, DIM_, PD_);
        }
        addpos_kernel<<<(B_ * N_ * DIM_ + 255) / 256, 256, 0, stream>>>(buf_hb, cls_tok, pos_emb, buf_x);

        for (int i = 0; i < DEPTH_; i++) {
            ln_kernel<<<ROWS / 4, 256, 0, stream>>>(buf_x, DIM_, ln1_g + i * DIM_,
                                                    ln1_b + i * DIM_, buf_hb, ROWS);
            mgemm9_kernel<0, bf16><<<dim3(9, GY2), 512, 0, stream>>>(
                buf_hb, wb_qkv + (size_t)i * 3 * INNER_ * DIM_, nullptr, nullptr, buf_qkv,
                ROWS, 3 * INNER_, DIM_);
            attn_mfma_kernel<<<dim3(B_, H_), 256, 0, stream>>>(buf_qkv, scale + i * H_, buf_hb);
            mgemm5_kernel<1, float><<<dim3(3, GY), 256, 0, stream>>>(
                buf_hb, wb_out + (size_t)i * DIM_ * INNER_, out_b + i * DIM_, buf_x, buf_x,
                ROWS, DIM_, INNER_);
            ln_kernel<<<ROWS / 4, 256, 0, stream>>>(buf_x, DIM_, ln2_g + i * DIM_,
                                                    ln2_b + i * DIM_, buf_hb, ROWS);
            int base = 0;
            for (int c = 0; c < fchunks; c++) {
                int mrows = (fchunks == 1) ? ROWS : ((c == 0) ? 6336 : 6272);
                int gy2 = (mrows + 255) / 256;
                int gy = (mrows + 127) / 128;
                mgemm9_kernel<2, bf16><<<dim3(12, gy2), 512, 0, stream>>>(
                    buf_hb + (size_t)base * DIM_, wb_ff1 + (size_t)i * MLP_ * DIM_,
                    ff_b1 + i * MLP_, nullptr, buf_ff, mrows, MLP_, DIM_);
                mgemm5_kernel<1, float><<<dim3(3, gy), 256, 0, stream>>>(
                    buf_ff, wb_ff2 + (size_t)i * DIM_ * MLP_, ff_b2 + i * DIM_,
                    buf_x + (size_t)base * DIM_, buf_x + (size_t)base * DIM_, mrows, DIM_, MLP_);
                base += mrows;
            }
        }

        ln_kernel<<<B_ / 4, 256, 0, stream>>>(buf_x, (long)N_ * DIM_, lnf_g, lnf_b, buf_cls, B_);
        head_kernel<<<250, 256, 0, stream>>>(buf_cls, head_w, head_b, (float*)d_out);
        diag_kernel<<<250, 256, 0, stream>>>(buf_x, (float*)d_out, 0, 1);
        return;
    }

    // ---- base tier: round-7 proven path (W f32 in-kernel convert) ----
    bf16* buf_cd   = (bf16*)(ws + 29048832);
    bf16* meanimg  = (bf16*)(ws + 29048832 + 22478848);
    bf16* buf_cls  = (bf16*)(ws + 58097664);

    mean_kernel<<<(B_ * 50176 + 255) / 256, 256, 0, stream>>>(img, meanimg);
    for (int c = 0; c < 2; c++) {
        int bp0 = c * 6272;
        patches_kernel<<<6272, 256, 0, stream>>>(img, meanimg, buf_cd, bp0, 6272);
        mgemm_kernel<0, bf16><<<dim3(DIM_ / 64, 49), 256, 0, stream>>>(
            buf_cd, patch_w, patch_b, nullptr, buf_hb + (size_t)bp0 * DIM_, 6272, DIM_, PD_);
    }
    addpos_kernel<<<(B_ * N_ * DIM_ + 255) / 256, 256, 0, stream>>>(buf_hb, cls_tok, pos_emb, buf_x);

    for (int i = 0; i < DEPTH_; i++) {
        ln_kernel<<<ROWS / 4, 256, 0, stream>>>(buf_x, DIM_, ln1_g + i * DIM_,
                                                ln1_b + i * DIM_, buf_hb, ROWS);
        mgemm_kernel<0, bf16><<<dim3((3 * INNER_) / 64, GY), 256, 0, stream>>>(
            buf_hb, qkv_w + (size_t)i * 3 * INNER_ * DIM_, nullptr, nullptr, buf_cd,
            ROWS, 3 * INNER_, DIM_);
        attn_mfma_kernel<<<dim3(B_, H_), 256, 0, stream>>>(buf_cd, scale + i * H_, buf_hb);
        mgemm_kernel<1, float><<<dim3(DIM_ / 64, GY), 256, 0, stream>>>(
            buf_hb, out_w + (size_t)i * DIM_ * INNER_, out_b + i * DIM_, buf_x, buf_x,
            ROWS, DIM_, INNER_);
        ln_kernel<<<ROWS / 4, 256, 0, stream>>>(buf_x, DIM_, ln2_g + i * DIM_,
                                                ln2_b + i * DIM_, buf_hb, ROWS);
        int base = 0;
        for (int c = 0; c < 2; c++) {
            int mrows = (c == 0) ? 6336 : 6272;
            int gy = (mrows + 127) / 128;
            mgemm_kernel<2, bf16><<<dim3(MLP_ / 64, gy), 256, 0, stream>>>(
                buf_hb + (size_t)base * DIM_, ff_w1 + (size_t)i * MLP_ * DIM_,
                ff_b1 + i * MLP_, nullptr, buf_cd, mrows, MLP_, DIM_);
            mgemm_kernel<1, float><<<dim3(DIM_ / 64, gy), 256, 0, stream>>>(
                buf_cd, ff_w2 + (size_t)i * DIM_ * MLP_, ff_b2 + i * DIM_,
                buf_x + (size_t)base * DIM_, buf_x + (size_t)base * DIM_, mrows, DIM_, MLP_);
            base += mrows;
        }
    }

    ln_kernel<<<B_ / 4, 256, 0, stream>>>(buf_x, (long)N_ * DIM_, lnf_g, lnf_b, buf_cls, B_);
    head_kernel<<<250, 256, 0, stream>>>(buf_cls, head_w, head_b, (float*)d_out);
    diag_kernel<<<250, 256, 0, stream>>>(buf_x, (float*)d_out, 0, 1);
}